// Round 3
// baseline (1297.670 us; speedup 1.0000x reference)
//
#include <hip/hip_runtime.h>

#define N_USERS 100000
#define N_ITEMS 200000
#define N_NODES (N_USERS + N_ITEMS)
#define EMB     64
#define NNZ     4000000

#define SCAN_BLOCK 256
#define SCAN_ITEMS 4
#define SCAN_TILE  (SCAN_BLOCK * SCAN_ITEMS)               // 1024
#define NUM_TILES  ((N_NODES + SCAN_TILE - 1) / SCAN_TILE) // 293

// coarse row-buckets: 1024 rows each
#define BSHIFT 10
#define BROWS  (1 << BSHIFT)                               // 1024 rows / bucket
#define NBUCK  ((N_NODES + BROWS - 1) >> BSHIFT)           // 293

// block-aggregated binning pass
#define AGG_THR    512
#define AGG_EPT    8
#define AGG_T      (AGG_THR * AGG_EPT)                     // 4096 edges / block
#define AGG_BLOCKS ((NNZ + AGG_T - 1) / AGG_T)             // 977
#define SCAN_N     512                                     // pow2 >= NBUCK

// place pass: LDS capacity per bucket (mean run 13653, std ~117 -> +14 sigma)
#define PCAP   15360
#define PITER  (PCAP / 1024)                               // 15

// ---------------------------------------------------------------------------
// non-temporal access helpers (steer Infinity-Cache allocation away from
// single-use streams; reusable data keeps default cacheable loads/stores)
// ---------------------------------------------------------------------------
typedef float f4v __attribute__((ext_vector_type(4)));
typedef float f2v __attribute__((ext_vector_type(2)));

__device__ __forceinline__ float4 ldnt4(const float* p) {
    f4v v = __builtin_nontemporal_load((const f4v*)p);
    return make_float4(v.x, v.y, v.z, v.w);
}
__device__ __forceinline__ void stnt4(float* p, float4 v) {
    f4v t = {v.x, v.y, v.z, v.w};
    __builtin_nontemporal_store(t, (f4v*)p);
}
__device__ __forceinline__ float2 ldnt2(const float2* p) {
    f2v v = __builtin_nontemporal_load((const f2v*)p);
    return make_float2(v.x, v.y);
}

// ===========================================================================
// CSR build
// ===========================================================================
__global__ void hist_kernel(const int* __restrict__ rows, int* __restrict__ cnt) {
    int e = blockIdx.x * blockDim.x + threadIdx.x;
    if (e < NNZ) atomicAdd(&cnt[__builtin_nontemporal_load(rows + e)], 1);
}

__global__ void scan1_kernel(const int* __restrict__ cnt,
                             int* __restrict__ excl,
                             int* __restrict__ tile_sums) {
    __shared__ int s[SCAN_BLOCK];
    int tid  = threadIdx.x;
    int base = blockIdx.x * SCAN_TILE + tid * SCAN_ITEMS;
    int v[SCAN_ITEMS];
    int sum = 0;
#pragma unroll
    for (int j = 0; j < SCAN_ITEMS; j++) {
        int idx = base + j;
        v[j] = (idx < N_NODES) ? cnt[idx] : 0;
        sum += v[j];
    }
    s[tid] = sum;
    __syncthreads();
    for (int off = 1; off < SCAN_BLOCK; off <<= 1) {
        int t = 0;
        if (tid >= off) t = s[tid - off];
        __syncthreads();
        if (tid >= off) s[tid] += t;
        __syncthreads();
    }
    int run = s[tid] - sum;
#pragma unroll
    for (int j = 0; j < SCAN_ITEMS; j++) {
        int idx = base + j;
        if (idx < N_NODES) excl[idx] = run;
        run += v[j];
    }
    if (tid == SCAN_BLOCK - 1) tile_sums[blockIdx.x] = s[tid];
}

__global__ void scan2_kernel(int* __restrict__ tile_sums) {
    __shared__ int s[512];
    int tid = threadIdx.x;
    int v = (tid < NUM_TILES) ? tile_sums[tid] : 0;
    s[tid] = v;
    __syncthreads();
    for (int off = 1; off < 512; off <<= 1) {
        int t = 0;
        if (tid >= off) t = s[tid - off];
        __syncthreads();
        if (tid >= off) s[tid] += t;
        __syncthreads();
    }
    if (tid < NUM_TILES) tile_sums[tid] = s[tid] - v;
}

__global__ void scan3_kernel(int* __restrict__ row_ptr,
                             const int* __restrict__ tile_sums,
                             int* __restrict__ cursor) {
    int i = blockIdx.x * blockDim.x + threadIdx.x;
    if (i < N_NODES) {
        int v = row_ptr[i] + tile_sums[i / SCAN_TILE];
        row_ptr[i] = v;
        cursor[i]  = v;
    }
    if (i == 0) row_ptr[N_NODES] = NNZ;
}

// bucket cursors (64B-padded) = CSR offset of bucket start
__global__ void binit_kernel(const int* __restrict__ row_ptr, int* __restrict__ bcur) {
    int b = blockIdx.x * blockDim.x + threadIdx.x;
    if (b < NBUCK) bcur[b * 16] = row_ptr[b << BSHIFT];
}

// pass 1 (block-aggregated): bin 4096 edges/block into coarse buckets via LDS
// counting-sort, reserve each bucket's run with ONE global atomic per
// (block,bucket), write runs contiguously & coalesced. rlo is packed into the
// high bits of the col field (col < 2^19, rlo 10 bits).
__global__ __launch_bounds__(AGG_THR)
void bucket_agg_kernel(const int*   __restrict__ rows,
                       const int*   __restrict__ cols,
                       const float* __restrict__ vals,
                       int*         __restrict__ bcur,
                       float2*      __restrict__ pay) {
    __shared__ int            cntS[SCAN_N];   // counts -> exclusive scan
    __shared__ int            hoff[SCAN_N];   // global run start per bucket
    __shared__ float2         payS[AGG_T];    // staged (packed col, val)
    __shared__ unsigned short bidS[AGG_T];    // bucket id per staged slot

    int tid  = threadIdx.x;
    int base = blockIdx.x * AGG_T;

    for (int i = tid; i < SCAN_N; i += AGG_THR) cntS[i] = 0;
    __syncthreads();

    // phase A: count (keep per-edge bucket/row-lo/local-pos packed in regs)
    unsigned pk[AGG_EPT];
#pragma unroll
    for (int j = 0; j < AGG_EPT; j++) {
        int e = base + j * AGG_THR + tid;
        pk[j] = 0xFFFFFFFFu;
        if (e < NNZ) {
            int r  = __builtin_nontemporal_load(rows + e);
            int b  = r >> BSHIFT;                    // 9 bits
            int lp = atomicAdd(&cntS[b], 1);         // <= 4095, 12 bits
            pk[j]  = ((unsigned)b << 22) | ((unsigned)(r & (BROWS - 1)) << 12)
                   | (unsigned)lp;
        }
    }
    __syncthreads();

    // exclusive scan of cntS (SCAN_N == AGG_THR, one element per thread)
    int v = cntS[tid];
    for (int off = 1; off < SCAN_N; off <<= 1) {
        int t = 0;
        if (tid >= off) t = cntS[tid - off];
        __syncthreads();
        if (tid >= off) cntS[tid] += t;
        __syncthreads();
    }
    int excl = cntS[tid] - v;

    // reserve global runs (one atomic per non-empty bucket)
    if (tid < NBUCK && v > 0) hoff[tid] = atomicAdd(&bcur[tid * 16], v);
    __syncthreads();
    cntS[tid] = excl;
    __syncthreads();

    // phase B: stage into LDS at counting-sort position
#pragma unroll
    for (int j = 0; j < AGG_EPT; j++) {
        if (pk[j] != 0xFFFFFFFFu) {
            int e   = base + j * AGG_THR + tid;
            int b   = pk[j] >> 22;
            int rl  = (pk[j] >> 12) & (BROWS - 1);
            int lp  = pk[j] & 0xFFF;
            int idx = cntS[b] + lp;
            unsigned packed = (unsigned)__builtin_nontemporal_load(cols + e)
                            | ((unsigned)rl << 19);
            payS[idx] = make_float2(__uint_as_float(packed),
                                    __builtin_nontemporal_load(vals + e));
            bidS[idx] = (unsigned short)b;
        }
    }
    __syncthreads();

    // write-out: contiguous per-bucket runs -> coalesced, line-dense
    int total = NNZ - base; if (total > AGG_T) total = AGG_T;
    for (int i = tid; i < total; i += AGG_THR) {
        int b = bidS[i];
        int g = hoff[b] + (i - cntS[b]);
        pay[g] = payS[i];
    }
}

// pass 2: one block per coarse bucket. Counting-sort the bucket's run by row
// ENTIRELY IN LDS (120 KB payload stage + 1024 counters), then stream the
// sorted run out sequentially -> every global store is full-line coalesced.
__global__ __launch_bounds__(1024)
void place_kernel(const int*    __restrict__ row_ptr,
                  const float2* __restrict__ pay,
                  int*          __restrict__ cursor,
                  float2*       __restrict__ edges) {
    __shared__ float2 payS[PCAP];   // 122880 B
    __shared__ int    cntS[BROWS];  //   4096 B
    int b   = blockIdx.x;
    int tid = threadIdx.x;
    int beg = row_ptr[b << BSHIFT];
    int endRow = (b + 1) << BSHIFT;
    if (endRow > N_NODES) endRow = N_NODES;
    int end = row_ptr[endRow];
    int run = end - beg;

    if (run > PCAP) {
        // fallback (statistically unreachable: PCAP = mean + 14 sigma)
        for (int i = beg + tid; i < end; i += 1024) {
            float2 p = pay[i];
            unsigned u = __float_as_uint(p.x);
            int r   = (b << BSHIFT) + (int)(u >> 19);
            int pos = atomicAdd(&cursor[r], 1);
            edges[pos] = make_float2(__uint_as_float(u & 0x7FFFFu), p.y);
        }
        return;
    }

    cntS[tid] = 0;
    __syncthreads();

    // phase A: pull edges into registers (fully unrolled -> static indexing),
    // histogram rows; atomic return value = within-row slot.
    unsigned eu[PITER]; float ev[PITER]; int elp[PITER];
#pragma unroll
    for (int j = 0; j < PITER; j++) {
        int i = beg + j * 1024 + tid;
        eu[j] = 0xFFFFFFFFu;
        if (i < end) {
            float2 p = ldnt2(&pay[i]);
            unsigned u = __float_as_uint(p.x);
            eu[j] = u;
            ev[j] = p.y;
            elp[j] = atomicAdd(&cntS[(u >> 19) & (BROWS - 1)], 1);
        }
    }
    __syncthreads();

    // inclusive scan of the 1024 row-counts; exclusive(r) = cntS[r-1]
    for (int off = 1; off < BROWS; off <<= 1) {
        int t = 0;
        if (tid >= off) t = cntS[tid - off];
        __syncthreads();
        if (tid >= off) cntS[tid] += t;
        __syncthreads();
    }

    // phase B: scatter into LDS at final sorted position
#pragma unroll
    for (int j = 0; j < PITER; j++) {
        if (eu[j] != 0xFFFFFFFFu) {
            int r    = (int)((eu[j] >> 19) & (BROWS - 1));
            int base = (r == 0) ? 0 : cntS[r - 1];
            payS[base + elp[j]] = make_float2(__uint_as_float(eu[j] & 0x7FFFFu), ev[j]);
        }
    }
    __syncthreads();

    // phase C: stream out sequentially — full-line coalesced stores
    // (normal stores: edges are re-read 3x by spmm, let them allocate)
    for (int i = tid; i < run; i += 1024) {
        edges[beg + i] = payS[i];
    }
}

// out = bufA = concat(user, item)
__global__ void init2_kernel(const float* __restrict__ user_t,
                             const float* __restrict__ item_t,
                             float* __restrict__ out,
                             float* __restrict__ bufA) {
    int i = blockIdx.x * blockDim.x + threadIdx.x;
    const int total4 = N_NODES * EMB / 4;
    if (i >= total4) return;
    int fi   = i * 4;
    int node = fi >> 6;
    int off  = fi & 63;
    float4 v;
    if (node < N_USERS)
        v = ldnt4(user_t + (size_t)node * EMB + off);
    else
        v = ldnt4(item_t + (size_t)(node - N_USERS) * EMB + off);
    stnt4(out + fi, v);          // out: single-use stream until layer-1 RMW
    *(float4*)(bufA + fi) = v;   // bufA: gathered by spmm1 -> keep cacheable
}

// SpMM: 4 rows per wave; lane = (quarter q = row, slot s = dims 4s..4s+3)
// Cache policy: edges + out RMW are single-use -> nt; x gather cacheable;
// y store NORMAL on purpose (y of layer k is the gather target of layer k+1,
// a cacheable store pre-warms it). Last layer (WY=false) skips y entirely.
template<bool WY>
__global__ void spmm4_kernel(const int*    __restrict__ rp,
                             const float2* __restrict__ edges,
                             const float*  __restrict__ x,
                             float*        __restrict__ y,
                             float*        __restrict__ out,
                             float scale) {
    int t    = blockIdx.x * blockDim.x + threadIdx.x;
    int wid  = t >> 6;
    int lane = t & 63;
    int q    = lane >> 4;
    int s    = lane & 15;
    int row  = (wid << 2) + q;
    if (row >= N_NODES) return;
    int i   = rp[row];
    int end = rp[row + 1];
    float4 acc = make_float4(0.f, 0.f, 0.f, 0.f);
    for (; i + 1 < end; i += 2) {
        float2 e0 = ldnt2(&edges[i]);
        float2 e1 = ldnt2(&edges[i + 1]);
        float4 a = *(const float4*)(x + ((size_t)__float_as_int(e0.x) << 6) + (s << 2));
        float4 b = *(const float4*)(x + ((size_t)__float_as_int(e1.x) << 6) + (s << 2));
        acc.x += e0.y * a.x + e1.y * b.x;
        acc.y += e0.y * a.y + e1.y * b.y;
        acc.z += e0.y * a.z + e1.y * b.z;
        acc.w += e0.y * a.w + e1.y * b.w;
    }
    if (i < end) {
        float2 e0 = ldnt2(&edges[i]);
        float4 a = *(const float4*)(x + ((size_t)__float_as_int(e0.x) << 6) + (s << 2));
        acc.x += e0.y * a.x;
        acc.y += e0.y * a.y;
        acc.z += e0.y * a.z;
        acc.w += e0.y * a.w;
    }
    size_t o = ((size_t)row << 6) + (s << 2);
    if (WY) *(float4*)(y + o) = acc;
    float4 ov = ldnt4(out + o);
    ov.x = (ov.x + acc.x) * scale;
    ov.y = (ov.y + acc.y) * scale;
    ov.z = (ov.z + acc.z) * scale;
    ov.w = (ov.w + acc.w) * scale;
    stnt4(out + o, ov);
}

// ===========================================================================
// Fallback atomic path (tiny ws only)
// ===========================================================================
__global__ void init_kernel(const float* __restrict__ user_t,
                            const float* __restrict__ item_t,
                            float* __restrict__ out,
                            float* __restrict__ bufA,
                            float* __restrict__ bufB) {
    int i = blockIdx.x * blockDim.x + threadIdx.x;
    const int total4 = N_NODES * EMB / 4;
    if (i >= total4) return;
    int fi   = i * 4;
    int node = fi >> 6;
    int off  = fi & 63;
    float4 v;
    if (node < N_USERS)
        v = *(const float4*)(user_t + (size_t)node * EMB + off);
    else
        v = *(const float4*)(item_t + (size_t)(node - N_USERS) * EMB + off);
    *(float4*)(out  + fi) = v;
    *(float4*)(bufA + fi) = v;
    *(float4*)(bufB + fi) = make_float4(0.f, 0.f, 0.f, 0.f);
}

__global__ void spmm_kernel(const int*   __restrict__ rows,
                            const int*   __restrict__ cols,
                            const float* __restrict__ vals,
                            const float* __restrict__ x,
                            float*       __restrict__ y) {
    int tid  = blockIdx.x * blockDim.x + threadIdx.x;
    int e    = tid >> 6;
    int lane = tid & 63;
    if (e >= NNZ) return;
    atomicAdd(&y[(size_t)rows[e] * EMB + lane], vals[e] * x[(size_t)cols[e] * EMB + lane]);
}

__global__ void acc_zero_kernel(float* __restrict__ out,
                                const float* __restrict__ src,
                                float* __restrict__ zbuf) {
    int i = blockIdx.x * blockDim.x + threadIdx.x;
    const int total4 = N_NODES * EMB / 4;
    if (i >= total4) return;
    int fi = i * 4;
    float4 o = *(float4*)(out + fi);
    float4 s = *(const float4*)(src + fi);
    o.x += s.x; o.y += s.y; o.z += s.z; o.w += s.w;
    *(float4*)(out  + fi) = o;
    *(float4*)(zbuf + fi) = make_float4(0.f, 0.f, 0.f, 0.f);
}

__global__ void final_kernel(float* __restrict__ out,
                             const float* __restrict__ src) {
    int i = blockIdx.x * blockDim.x + threadIdx.x;
    const int total4 = N_NODES * EMB / 4;
    if (i >= total4) return;
    int fi = i * 4;
    float4 o = *(float4*)(out + fi);
    float4 s = *(const float4*)(src + fi);
    o.x = (o.x + s.x) * 0.25f;
    o.y = (o.y + s.y) * 0.25f;
    o.z = (o.z + s.z) * 0.25f;
    o.w = (o.w + s.w) * 0.25f;
    *(float4*)(out + fi) = o;
}

// ===========================================================================
extern "C" void kernel_launch(void* const* d_in, const int* in_sizes, int n_in,
                              void* d_out, int out_size, void* d_ws, size_t ws_size,
                              hipStream_t stream) {
    const float* user_t = (const float*)d_in[0];
    const float* item_t = (const float*)d_in[1];
    const int*   rows   = (const int*)d_in[2];
    const int*   cols   = (const int*)d_in[3];
    const float* vals   = (const float*)d_in[4];
    float* out = (float*)d_out;

    const size_t emb_elems = (size_t)N_NODES * EMB;
    const int total4    = N_NODES * EMB / 4;
    const int ew_blocks = (total4 + 255) / 256;

    // ---- workspace layout (same footprint as before) ----
    char* p = (char*)d_ws;
    float*  bufA      = (float*)p;  p += emb_elems * 4;           // 76.8 MB
    float*  bufB      = (float*)p;  p += emb_elems * 4;           // 76.8 MB
    float2* edges     = (float2*)p; p += (size_t)NNZ * 8;         // 32 MB
    int*    row_ptr   = (int*)p;    p += (size_t)(N_NODES + 1) * 4;
    int*    cursor    = (int*)p;    p += (size_t)N_NODES * 4;
    int*    cnt       = (int*)p;    p += (size_t)N_NODES * 4;
    int*    tile_sums = (int*)p;    p += (size_t)NUM_TILES * 4;
    size_t need = (size_t)(p - (char*)d_ws);

    // aliases: pay lives in bufB (dead until first spmm); bcur lives in cnt
    // (cnt dead after scan1).
    float2* pay  = (float2*)bufB;                                 // 32 MB
    int*    bcur = cnt;                                           // 18.75 KB used

    if (ws_size >= need) {
        hipMemsetAsync(cnt, 0, (size_t)N_NODES * 4, stream);
        hist_kernel <<<(NNZ + 255) / 256, 256, 0, stream>>>(rows, cnt);
        scan1_kernel<<<NUM_TILES, SCAN_BLOCK, 0, stream>>>(cnt, row_ptr, tile_sums);
        scan2_kernel<<<1, 512, 0, stream>>>(tile_sums);
        scan3_kernel<<<(N_NODES + 255) / 256, 256, 0, stream>>>(row_ptr, tile_sums, cursor);
        binit_kernel<<<(NBUCK + 255) / 256, 256, 0, stream>>>(row_ptr, bcur);
        bucket_agg_kernel<<<AGG_BLOCKS, AGG_THR, 0, stream>>>(rows, cols, vals, bcur, pay);
        place_kernel<<<NBUCK, 1024, 0, stream>>>(row_ptr, pay, cursor, edges);

        init2_kernel<<<ew_blocks, 256, 0, stream>>>(user_t, item_t, out, bufA);

        const int spmm_blocks = (int)(((size_t)N_NODES / 4 * 64 + 255) / 256); // 18750
        spmm4_kernel<true ><<<spmm_blocks, 256, 0, stream>>>(row_ptr, edges, bufA, bufB, out, 1.0f);
        spmm4_kernel<true ><<<spmm_blocks, 256, 0, stream>>>(row_ptr, edges, bufB, bufA, out, 1.0f);
        spmm4_kernel<false><<<spmm_blocks, 256, 0, stream>>>(row_ptr, edges, bufA, bufB, out, 0.25f);
    } else {
        const int spmm_blocks = (int)(((size_t)NNZ * 64 + 255) / 256);
        init_kernel<<<ew_blocks, 256, 0, stream>>>(user_t, item_t, out, bufA, bufB);
        spmm_kernel<<<spmm_blocks, 256, 0, stream>>>(rows, cols, vals, bufA, bufB);
        acc_zero_kernel<<<ew_blocks, 256, 0, stream>>>(out, bufB, bufA);
        spmm_kernel<<<spmm_blocks, 256, 0, stream>>>(rows, cols, vals, bufB, bufA);
        acc_zero_kernel<<<ew_blocks, 256, 0, stream>>>(out, bufA, bufB);
        spmm_kernel<<<spmm_blocks, 256, 0, stream>>>(rows, cols, vals, bufA, bufB);
        final_kernel<<<ew_blocks, 256, 0, stream>>>(out, bufB);
    }
}

// Round 4
// 958.122 us; speedup vs baseline: 1.3544x; 1.3544x over previous
//
#include <hip/hip_runtime.h>

#define N_USERS 100000
#define N_ITEMS 200000
#define N_NODES (N_USERS + N_ITEMS)
#define EMB     64
#define NNZ     4000000

#define SCAN_BLOCK 256
#define SCAN_ITEMS 4
#define SCAN_TILE  (SCAN_BLOCK * SCAN_ITEMS)               // 1024
#define NUM_TILES  ((N_NODES + SCAN_TILE - 1) / SCAN_TILE) // 293

// coarse row-buckets: 1024 rows each
#define BSHIFT 10
#define BROWS  (1 << BSHIFT)                               // 1024 rows / bucket
#define NBUCK  ((N_NODES + BROWS - 1) >> BSHIFT)           // 293

// block-aggregated binning pass
#define AGG_THR    512
#define AGG_EPT    8
#define AGG_T      (AGG_THR * AGG_EPT)                     // 4096 edges / block
#define AGG_BLOCKS ((NNZ + AGG_T - 1) / AGG_T)             // 977
#define SCAN_N     512                                     // pow2 >= NBUCK

// place pass: LDS capacity per bucket (mean run 13653, std ~117 -> +14 sigma)
#define PCAP   15360
#define PITER  (PCAP / 1024)                               // 15

// NOTE (round-3 post-mortem): __builtin_nontemporal_load on gfx950 acts as a
// last-use/invalidating load; on dirty (recently-written) lines it triggered
// ~35x WRITE_SIZE amplification (place_kernel: 33MB logical -> 1.1GB at HBM,
// 60us -> 351us). Do NOT use nontemporal hints on data that is dirty in cache
// or re-read later. All memory ops below are plain cached accesses.

// ===========================================================================
// CSR build
// ===========================================================================
__global__ void hist_kernel(const int* __restrict__ rows, int* __restrict__ cnt) {
    int e = blockIdx.x * blockDim.x + threadIdx.x;
    if (e < NNZ) atomicAdd(&cnt[rows[e]], 1);
}

__global__ void scan1_kernel(const int* __restrict__ cnt,
                             int* __restrict__ excl,
                             int* __restrict__ tile_sums) {
    __shared__ int s[SCAN_BLOCK];
    int tid  = threadIdx.x;
    int base = blockIdx.x * SCAN_TILE + tid * SCAN_ITEMS;
    int v[SCAN_ITEMS];
    int sum = 0;
#pragma unroll
    for (int j = 0; j < SCAN_ITEMS; j++) {
        int idx = base + j;
        v[j] = (idx < N_NODES) ? cnt[idx] : 0;
        sum += v[j];
    }
    s[tid] = sum;
    __syncthreads();
    for (int off = 1; off < SCAN_BLOCK; off <<= 1) {
        int t = 0;
        if (tid >= off) t = s[tid - off];
        __syncthreads();
        if (tid >= off) s[tid] += t;
        __syncthreads();
    }
    int run = s[tid] - sum;
#pragma unroll
    for (int j = 0; j < SCAN_ITEMS; j++) {
        int idx = base + j;
        if (idx < N_NODES) excl[idx] = run;
        run += v[j];
    }
    if (tid == SCAN_BLOCK - 1) tile_sums[blockIdx.x] = s[tid];
}

__global__ void scan2_kernel(int* __restrict__ tile_sums) {
    __shared__ int s[512];
    int tid = threadIdx.x;
    int v = (tid < NUM_TILES) ? tile_sums[tid] : 0;
    s[tid] = v;
    __syncthreads();
    for (int off = 1; off < 512; off <<= 1) {
        int t = 0;
        if (tid >= off) t = s[tid - off];
        __syncthreads();
        if (tid >= off) s[tid] += t;
        __syncthreads();
    }
    if (tid < NUM_TILES) tile_sums[tid] = s[tid] - v;
}

__global__ void scan3_kernel(int* __restrict__ row_ptr,
                             const int* __restrict__ tile_sums,
                             int* __restrict__ cursor) {
    int i = blockIdx.x * blockDim.x + threadIdx.x;
    if (i < N_NODES) {
        int v = row_ptr[i] + tile_sums[i / SCAN_TILE];
        row_ptr[i] = v;
        cursor[i]  = v;
    }
    if (i == 0) row_ptr[N_NODES] = NNZ;
}

// bucket cursors (64B-padded) = CSR offset of bucket start
__global__ void binit_kernel(const int* __restrict__ row_ptr, int* __restrict__ bcur) {
    int b = blockIdx.x * blockDim.x + threadIdx.x;
    if (b < NBUCK) bcur[b * 16] = row_ptr[b << BSHIFT];
}

// pass 1 (block-aggregated): bin 4096 edges/block into coarse buckets via LDS
// counting-sort, reserve each bucket's run with ONE global atomic per
// (block,bucket), write runs contiguously & coalesced. rlo is packed into the
// high bits of the col field (col < 2^19, rlo 10 bits).
__global__ __launch_bounds__(AGG_THR)
void bucket_agg_kernel(const int*   __restrict__ rows,
                       const int*   __restrict__ cols,
                       const float* __restrict__ vals,
                       int*         __restrict__ bcur,
                       float2*      __restrict__ pay) {
    __shared__ int            cntS[SCAN_N];   // counts -> exclusive scan
    __shared__ int            hoff[SCAN_N];   // global run start per bucket
    __shared__ float2         payS[AGG_T];    // staged (packed col, val)
    __shared__ unsigned short bidS[AGG_T];    // bucket id per staged slot

    int tid  = threadIdx.x;
    int base = blockIdx.x * AGG_T;

    for (int i = tid; i < SCAN_N; i += AGG_THR) cntS[i] = 0;
    __syncthreads();

    // phase A: count (keep per-edge bucket/row-lo/local-pos packed in regs)
    unsigned pk[AGG_EPT];
#pragma unroll
    for (int j = 0; j < AGG_EPT; j++) {
        int e = base + j * AGG_THR + tid;
        pk[j] = 0xFFFFFFFFu;
        if (e < NNZ) {
            int r  = rows[e];
            int b  = r >> BSHIFT;                    // 9 bits
            int lp = atomicAdd(&cntS[b], 1);         // <= 4095, 12 bits
            pk[j]  = ((unsigned)b << 22) | ((unsigned)(r & (BROWS - 1)) << 12)
                   | (unsigned)lp;
        }
    }
    __syncthreads();

    // exclusive scan of cntS (SCAN_N == AGG_THR, one element per thread)
    int v = cntS[tid];
    for (int off = 1; off < SCAN_N; off <<= 1) {
        int t = 0;
        if (tid >= off) t = cntS[tid - off];
        __syncthreads();
        if (tid >= off) cntS[tid] += t;
        __syncthreads();
    }
    int excl = cntS[tid] - v;

    // reserve global runs (one atomic per non-empty bucket)
    if (tid < NBUCK && v > 0) hoff[tid] = atomicAdd(&bcur[tid * 16], v);
    __syncthreads();
    cntS[tid] = excl;
    __syncthreads();

    // phase B: stage into LDS at counting-sort position
#pragma unroll
    for (int j = 0; j < AGG_EPT; j++) {
        if (pk[j] != 0xFFFFFFFFu) {
            int e   = base + j * AGG_THR + tid;
            int b   = pk[j] >> 22;
            int rl  = (pk[j] >> 12) & (BROWS - 1);
            int lp  = pk[j] & 0xFFF;
            int idx = cntS[b] + lp;
            unsigned packed = (unsigned)cols[e] | ((unsigned)rl << 19);
            payS[idx] = make_float2(__uint_as_float(packed), vals[e]);
            bidS[idx] = (unsigned short)b;
        }
    }
    __syncthreads();

    // write-out: contiguous per-bucket runs -> coalesced, line-dense
    int total = NNZ - base; if (total > AGG_T) total = AGG_T;
    for (int i = tid; i < total; i += AGG_THR) {
        int b = bidS[i];
        int g = hoff[b] + (i - cntS[b]);
        pay[g] = payS[i];
    }
}

// pass 2: one block per coarse bucket. Counting-sort the bucket's run by row
// ENTIRELY IN LDS (120 KB payload stage + 1024 counters), then stream the
// sorted run out sequentially -> every global store is full-line coalesced.
__global__ __launch_bounds__(1024)
void place_kernel(const int*    __restrict__ row_ptr,
                  const float2* __restrict__ pay,
                  int*          __restrict__ cursor,
                  float2*       __restrict__ edges) {
    __shared__ float2 payS[PCAP];   // 122880 B
    __shared__ int    cntS[BROWS];  //   4096 B
    int b   = blockIdx.x;
    int tid = threadIdx.x;
    int beg = row_ptr[b << BSHIFT];
    int endRow = (b + 1) << BSHIFT;
    if (endRow > N_NODES) endRow = N_NODES;
    int end = row_ptr[endRow];
    int run = end - beg;

    if (run > PCAP) {
        // fallback (statistically unreachable: PCAP = mean + 14 sigma)
        for (int i = beg + tid; i < end; i += 1024) {
            float2 p = pay[i];
            unsigned u = __float_as_uint(p.x);
            int r   = (b << BSHIFT) + (int)(u >> 19);
            int pos = atomicAdd(&cursor[r], 1);
            edges[pos] = make_float2(__uint_as_float(u & 0x7FFFFu), p.y);
        }
        return;
    }

    cntS[tid] = 0;
    __syncthreads();

    // phase A: pull edges into registers (fully unrolled -> static indexing),
    // histogram rows; atomic return value = within-row slot.
    unsigned eu[PITER]; float ev[PITER]; int elp[PITER];
#pragma unroll
    for (int j = 0; j < PITER; j++) {
        int i = beg + j * 1024 + tid;
        eu[j] = 0xFFFFFFFFu;
        if (i < end) {
            float2 p = pay[i];
            unsigned u = __float_as_uint(p.x);
            eu[j] = u;
            ev[j] = p.y;
            elp[j] = atomicAdd(&cntS[(u >> 19) & (BROWS - 1)], 1);
        }
    }
    __syncthreads();

    // inclusive scan of the 1024 row-counts; exclusive(r) = cntS[r-1]
    for (int off = 1; off < BROWS; off <<= 1) {
        int t = 0;
        if (tid >= off) t = cntS[tid - off];
        __syncthreads();
        if (tid >= off) cntS[tid] += t;
        __syncthreads();
    }

    // phase B: scatter into LDS at final sorted position
#pragma unroll
    for (int j = 0; j < PITER; j++) {
        if (eu[j] != 0xFFFFFFFFu) {
            int r    = (int)((eu[j] >> 19) & (BROWS - 1));
            int base = (r == 0) ? 0 : cntS[r - 1];
            payS[base + elp[j]] = make_float2(__uint_as_float(eu[j] & 0x7FFFFu), ev[j]);
        }
    }
    __syncthreads();

    // phase C: stream out sequentially — full-line coalesced stores
    for (int i = tid; i < run; i += 1024) {
        edges[beg + i] = payS[i];
    }
}

// out = bufA = concat(user, item)
__global__ void init2_kernel(const float* __restrict__ user_t,
                             const float* __restrict__ item_t,
                             float* __restrict__ out,
                             float* __restrict__ bufA) {
    int i = blockIdx.x * blockDim.x + threadIdx.x;
    const int total4 = N_NODES * EMB / 4;
    if (i >= total4) return;
    int fi   = i * 4;
    int node = fi >> 6;
    int off  = fi & 63;
    float4 v;
    if (node < N_USERS)
        v = *(const float4*)(user_t + (size_t)node * EMB + off);
    else
        v = *(const float4*)(item_t + (size_t)(node - N_USERS) * EMB + off);
    *(float4*)(out  + fi) = v;
    *(float4*)(bufA + fi) = v;
}

// SpMM, half-dim variant: each dispatch covers 32 of the 64 embedding floats
// (dhalf selects which half). Working set per dispatch = 38.5MB x-half +
// 37MB y-half + 32MB edges ~= 107MB << 256MB LLC, so the random x-gather is
// served from Infinity Cache instead of re-fetching HBM ~5.6x (round-2 FETCH
// was 539MB/layer vs ~110 compulsory). Cost: edges read twice per layer
// (2nd read LLC-hit). 8 rows per wave; lane = (q=row, s=4-float slot).
template<bool WY>
__global__ void spmm4h_kernel(const int*    __restrict__ rp,
                              const float2* __restrict__ edges,
                              const float*  __restrict__ x,
                              float*        __restrict__ y,
                              float*        __restrict__ out,
                              float scale, int dhalf) {
    int t    = blockIdx.x * blockDim.x + threadIdx.x;
    int wid  = t >> 6;
    int lane = t & 63;
    int q    = lane >> 3;              // 0..7: row within wave
    int s    = lane & 7;               // 0..7: 4-float slot within half
    int row  = (wid << 3) + q;
    if (row >= N_NODES) return;
    int i    = rp[row];
    int end  = rp[row + 1];
    int doff = (dhalf << 5) + (s << 2);
    float4 acc = make_float4(0.f, 0.f, 0.f, 0.f);
    for (; i + 1 < end; i += 2) {
        float2 e0 = edges[i];
        float2 e1 = edges[i + 1];
        float4 a = *(const float4*)(x + ((size_t)__float_as_int(e0.x) << 6) + doff);
        float4 b = *(const float4*)(x + ((size_t)__float_as_int(e1.x) << 6) + doff);
        acc.x += e0.y * a.x + e1.y * b.x;
        acc.y += e0.y * a.y + e1.y * b.y;
        acc.z += e0.y * a.z + e1.y * b.z;
        acc.w += e0.y * a.w + e1.y * b.w;
    }
    if (i < end) {
        float2 e0 = edges[i];
        float4 a = *(const float4*)(x + ((size_t)__float_as_int(e0.x) << 6) + doff);
        acc.x += e0.y * a.x;
        acc.y += e0.y * a.y;
        acc.z += e0.y * a.z;
        acc.w += e0.y * a.w;
    }
    size_t o = ((size_t)row << 6) + doff;
    if (WY) *(float4*)(y + o) = acc;
    float4 ov = *(float4*)(out + o);
    ov.x = (ov.x + acc.x) * scale;
    ov.y = (ov.y + acc.y) * scale;
    ov.z = (ov.z + acc.z) * scale;
    ov.w = (ov.w + acc.w) * scale;
    *(float4*)(out + o) = ov;
}

// ===========================================================================
// Fallback atomic path (tiny ws only)
// ===========================================================================
__global__ void init_kernel(const float* __restrict__ user_t,
                            const float* __restrict__ item_t,
                            float* __restrict__ out,
                            float* __restrict__ bufA,
                            float* __restrict__ bufB) {
    int i = blockIdx.x * blockDim.x + threadIdx.x;
    const int total4 = N_NODES * EMB / 4;
    if (i >= total4) return;
    int fi   = i * 4;
    int node = fi >> 6;
    int off  = fi & 63;
    float4 v;
    if (node < N_USERS)
        v = *(const float4*)(user_t + (size_t)node * EMB + off);
    else
        v = *(const float4*)(item_t + (size_t)(node - N_USERS) * EMB + off);
    *(float4*)(out  + fi) = v;
    *(float4*)(bufA + fi) = v;
    *(float4*)(bufB + fi) = make_float4(0.f, 0.f, 0.f, 0.f);
}

__global__ void spmm_kernel(const int*   __restrict__ rows,
                            const int*   __restrict__ cols,
                            const float* __restrict__ vals,
                            const float* __restrict__ x,
                            float*       __restrict__ y) {
    int tid  = blockIdx.x * blockDim.x + threadIdx.x;
    int e    = tid >> 6;
    int lane = tid & 63;
    if (e >= NNZ) return;
    atomicAdd(&y[(size_t)rows[e] * EMB + lane], vals[e] * x[(size_t)cols[e] * EMB + lane]);
}

__global__ void acc_zero_kernel(float* __restrict__ out,
                                const float* __restrict__ src,
                                float* __restrict__ zbuf) {
    int i = blockIdx.x * blockDim.x + threadIdx.x;
    const int total4 = N_NODES * EMB / 4;
    if (i >= total4) return;
    int fi = i * 4;
    float4 o = *(float4*)(out + fi);
    float4 s = *(const float4*)(src + fi);
    o.x += s.x; o.y += s.y; o.z += s.z; o.w += s.w;
    *(float4*)(out  + fi) = o;
    *(float4*)(zbuf + fi) = make_float4(0.f, 0.f, 0.f, 0.f);
}

__global__ void final_kernel(float* __restrict__ out,
                             const float* __restrict__ src) {
    int i = blockIdx.x * blockDim.x + threadIdx.x;
    const int total4 = N_NODES * EMB / 4;
    if (i >= total4) return;
    int fi = i * 4;
    float4 o = *(float4*)(out + fi);
    float4 s = *(const float4*)(src + fi);
    o.x = (o.x + s.x) * 0.25f;
    o.y = (o.y + s.y) * 0.25f;
    o.z = (o.z + s.z) * 0.25f;
    o.w = (o.w + s.w) * 0.25f;
    *(float4*)(out + fi) = o;
}

// ===========================================================================
extern "C" void kernel_launch(void* const* d_in, const int* in_sizes, int n_in,
                              void* d_out, int out_size, void* d_ws, size_t ws_size,
                              hipStream_t stream) {
    const float* user_t = (const float*)d_in[0];
    const float* item_t = (const float*)d_in[1];
    const int*   rows   = (const int*)d_in[2];
    const int*   cols   = (const int*)d_in[3];
    const float* vals   = (const float*)d_in[4];
    float* out = (float*)d_out;

    const size_t emb_elems = (size_t)N_NODES * EMB;
    const int total4    = N_NODES * EMB / 4;
    const int ew_blocks = (total4 + 255) / 256;

    // ---- workspace layout (same footprint as before) ----
    char* p = (char*)d_ws;
    float*  bufA      = (float*)p;  p += emb_elems * 4;           // 76.8 MB
    float*  bufB      = (float*)p;  p += emb_elems * 4;           // 76.8 MB
    float2* edges     = (float2*)p; p += (size_t)NNZ * 8;         // 32 MB
    int*    row_ptr   = (int*)p;    p += (size_t)(N_NODES + 1) * 4;
    int*    cursor    = (int*)p;    p += (size_t)N_NODES * 4;
    int*    cnt       = (int*)p;    p += (size_t)N_NODES * 4;
    int*    tile_sums = (int*)p;    p += (size_t)NUM_TILES * 4;
    size_t need = (size_t)(p - (char*)d_ws);

    // aliases: pay lives in bufB (dead until first spmm); bcur lives in cnt
    // (cnt dead after scan1).
    float2* pay  = (float2*)bufB;                                 // 32 MB
    int*    bcur = cnt;                                           // 18.75 KB used

    if (ws_size >= need) {
        hipMemsetAsync(cnt, 0, (size_t)N_NODES * 4, stream);
        hist_kernel <<<(NNZ + 255) / 256, 256, 0, stream>>>(rows, cnt);
        scan1_kernel<<<NUM_TILES, SCAN_BLOCK, 0, stream>>>(cnt, row_ptr, tile_sums);
        scan2_kernel<<<1, 512, 0, stream>>>(tile_sums);
        scan3_kernel<<<(N_NODES + 255) / 256, 256, 0, stream>>>(row_ptr, tile_sums, cursor);
        binit_kernel<<<(NBUCK + 255) / 256, 256, 0, stream>>>(row_ptr, bcur);
        bucket_agg_kernel<<<AGG_BLOCKS, AGG_THR, 0, stream>>>(rows, cols, vals, bcur, pay);
        place_kernel<<<NBUCK, 1024, 0, stream>>>(row_ptr, pay, cursor, edges);

        init2_kernel<<<ew_blocks, 256, 0, stream>>>(user_t, item_t, out, bufA);

        // half-dim SpMM: 8 rows/wave -> N_NODES/8 waves
        const int spmmh_blocks = (int)(((size_t)N_NODES / 8 * 64 + 255) / 256); // 9375
        spmm4h_kernel<true ><<<spmmh_blocks, 256, 0, stream>>>(row_ptr, edges, bufA, bufB, out, 1.0f, 0);
        spmm4h_kernel<true ><<<spmmh_blocks, 256, 0, stream>>>(row_ptr, edges, bufA, bufB, out, 1.0f, 1);
        spmm4h_kernel<true ><<<spmmh_blocks, 256, 0, stream>>>(row_ptr, edges, bufB, bufA, out, 1.0f, 0);
        spmm4h_kernel<true ><<<spmmh_blocks, 256, 0, stream>>>(row_ptr, edges, bufB, bufA, out, 1.0f, 1);
        spmm4h_kernel<false><<<spmmh_blocks, 256, 0, stream>>>(row_ptr, edges, bufA, bufB, out, 0.25f, 0);
        spmm4h_kernel<false><<<spmmh_blocks, 256, 0, stream>>>(row_ptr, edges, bufA, bufB, out, 0.25f, 1);
    } else {
        const int spmm_blocks = (int)(((size_t)NNZ * 64 + 255) / 256);
        init_kernel<<<ew_blocks, 256, 0, stream>>>(user_t, item_t, out, bufA, bufB);
        spmm_kernel<<<spmm_blocks, 256, 0, stream>>>(rows, cols, vals, bufA, bufB);
        acc_zero_kernel<<<ew_blocks, 256, 0, stream>>>(out, bufB, bufA);
        spmm_kernel<<<spmm_blocks, 256, 0, stream>>>(rows, cols, vals, bufB, bufA);
        acc_zero_kernel<<<ew_blocks, 256, 0, stream>>>(out, bufA, bufB);
        spmm_kernel<<<spmm_blocks, 256, 0, stream>>>(rows, cols, vals, bufA, bufB);
        final_kernel<<<ew_blocks, 256, 0, stream>>>(out, bufB);
    }
}

// Round 5
// 750.413 us; speedup vs baseline: 1.7293x; 1.2768x over previous
//
#include <hip/hip_runtime.h>

#define N_USERS 100000
#define N_ITEMS 200000
#define N_NODES (N_USERS + N_ITEMS)
#define EMB     64
#define NNZ     4000000

// coarse row-buckets: 1024 rows each
#define BSHIFT 10
#define BROWS  (1 << BSHIFT)                               // 1024 rows / bucket
#define NBUCK  ((N_NODES + BROWS - 1) >> BSHIFT)           // 293

// block-aggregated binning pass
#define AGG_THR    512
#define AGG_EPT    8
#define AGG_T      (AGG_THR * AGG_EPT)                     // 4096 edges / block
#define AGG_BLOCKS ((NNZ + AGG_T - 1) / AGG_T)             // 977
#define SCAN_N     512                                     // pow2 >= NBUCK

// bucket segment capacity (mean fill 13652, sigma ~117 -> +23 sigma headroom)
#define SEGCAP 16384
#define PCAP   SEGCAP
#define PITER  (PCAP / 1024)                               // 16

// NOTE (round-3 post-mortem): __builtin_nontemporal_load on gfx950 acts as a
// last-use/invalidating load; on dirty lines it caused ~35x WRITE_SIZE
// amplification. Plain cached accesses only.
// NOTE (round-4 post-mortem): 4M fine-grained global atomicAdds (hist) cost
// ~32B HBM write traffic each (125MB for a 1.2MB array) -- device-scope
// atomics resolve at memory. Aggregate in LDS first; the CSR build below has
// no per-edge global atomics at all.

// ===========================================================================
// CSR build (histogram-free, bucket-segmented)
// ===========================================================================

// pass 1 (block-aggregated): bin 4096 edges/block into coarse buckets via LDS
// counting-sort; reserve each bucket's run with ONE global atomic per
// (block,bucket) on bcnt; write runs contiguously into the bucket's fixed
// segment of pay. rlo packed into high bits of col (col < 2^19, rlo 10 bits).
__global__ __launch_bounds__(AGG_THR)
void bucket_agg_kernel(const int*   __restrict__ rows,
                       const int*   __restrict__ cols,
                       const float* __restrict__ vals,
                       int*         __restrict__ bcnt,   // [NBUCK*16] zeroed
                       float2*      __restrict__ pay) {  // [NBUCK*SEGCAP]
    __shared__ int            cntS[SCAN_N];   // counts -> exclusive scan
    __shared__ int            hoff[SCAN_N];   // segment offset per bucket
    __shared__ float2         payS[AGG_T];    // staged (packed col, val)
    __shared__ unsigned short bidS[AGG_T];    // bucket id per staged slot

    int tid  = threadIdx.x;
    int base = blockIdx.x * AGG_T;

    for (int i = tid; i < SCAN_N; i += AGG_THR) cntS[i] = 0;
    __syncthreads();

    // phase A: count (keep per-edge bucket/row-lo/local-pos packed in regs)
    unsigned pk[AGG_EPT];
#pragma unroll
    for (int j = 0; j < AGG_EPT; j++) {
        int e = base + j * AGG_THR + tid;
        pk[j] = 0xFFFFFFFFu;
        if (e < NNZ) {
            int r  = rows[e];
            int b  = r >> BSHIFT;                    // 9 bits
            int lp = atomicAdd(&cntS[b], 1);         // <= 4095, 12 bits
            pk[j]  = ((unsigned)b << 22) | ((unsigned)(r & (BROWS - 1)) << 12)
                   | (unsigned)lp;
        }
    }
    __syncthreads();

    // exclusive scan of cntS (SCAN_N == AGG_THR, one element per thread)
    int v = cntS[tid];
    for (int off = 1; off < SCAN_N; off <<= 1) {
        int t = 0;
        if (tid >= off) t = cntS[tid - off];
        __syncthreads();
        if (tid >= off) cntS[tid] += t;
        __syncthreads();
    }
    int excl = cntS[tid] - v;

    // reserve segment runs (one atomic per non-empty bucket)
    if (tid < NBUCK && v > 0) hoff[tid] = atomicAdd(&bcnt[tid * 16], v);
    __syncthreads();
    cntS[tid] = excl;
    __syncthreads();

    // phase B: stage into LDS at counting-sort position
#pragma unroll
    for (int j = 0; j < AGG_EPT; j++) {
        if (pk[j] != 0xFFFFFFFFu) {
            int e   = base + j * AGG_THR + tid;
            int b   = pk[j] >> 22;
            int rl  = (pk[j] >> 12) & (BROWS - 1);
            int lp  = pk[j] & 0xFFF;
            int idx = cntS[b] + lp;
            unsigned packed = (unsigned)cols[e] | ((unsigned)rl << 19);
            payS[idx] = make_float2(__uint_as_float(packed), vals[e]);
            bidS[idx] = (unsigned short)b;
        }
    }
    __syncthreads();

    // write-out: contiguous per-bucket runs into fixed segments
    int total = NNZ - base; if (total > AGG_T) total = AGG_T;
    for (int i = tid; i < total; i += AGG_THR) {
        int b   = bidS[i];
        int pos = hoff[b] + (i - cntS[b]);
        if (pos < SEGCAP)   // 23-sigma safety clamp
            pay[(size_t)b * SEGCAP + pos] = payS[i];
    }
}

// tiny pass: exclusive-scan the 293 bucket totals -> bbase; seal row_ptr end.
__global__ void bscan_kernel(const int* __restrict__ bcnt,
                             int* __restrict__ bbase,
                             int* __restrict__ row_ptr) {
    __shared__ int s[512];
    int tid = threadIdx.x;
    int v = 0;
    if (tid < NBUCK) {
        v = bcnt[tid * 16];
        if (v > SEGCAP) v = SEGCAP;
    }
    s[tid] = v;
    __syncthreads();
    for (int off = 1; off < 512; off <<= 1) {
        int t = 0;
        if (tid >= off) t = s[tid - off];
        __syncthreads();
        if (tid >= off) s[tid] += t;
        __syncthreads();
    }
    if (tid < NBUCK) bbase[tid] = s[tid] - v;
    if (tid == 511) bbase[NBUCK] = s[511];
    if (tid == 0)   row_ptr[N_NODES] = NNZ;
}

// pass 2: one block per coarse bucket. Counting-sort the bucket's segment by
// row ENTIRELY IN LDS (128 KB payload stage + 1024 counters), emit this
// bucket's row_ptr slice, then stream the sorted run out sequentially ->
// every global store is full-line coalesced.
__global__ __launch_bounds__(1024)
void place_kernel(const int*    __restrict__ bcnt,
                  const int*    __restrict__ bbase,
                  const float2* __restrict__ pay,
                  int*          __restrict__ row_ptr,
                  float2*       __restrict__ edges) {
    __shared__ float2 payS[PCAP];   // 131072 B
    __shared__ int    cntS[BROWS];  //   4096 B
    int b   = blockIdx.x;
    int tid = threadIdx.x;
    int run = bcnt[b * 16]; if (run > PCAP) run = PCAP;
    int beg = bbase[b];
    const float2* seg = pay + (size_t)b * SEGCAP;

    cntS[tid] = 0;
    __syncthreads();

    // phase A: pull edges into registers (fully unrolled -> static indexing),
    // histogram rows; atomic return value = within-row slot.
    unsigned eu[PITER]; float ev[PITER]; int elp[PITER];
#pragma unroll
    for (int j = 0; j < PITER; j++) {
        int i = j * 1024 + tid;
        eu[j] = 0xFFFFFFFFu;
        if (i < run) {
            float2 p = seg[i];
            unsigned u = __float_as_uint(p.x);
            eu[j] = u;
            ev[j] = p.y;
            elp[j] = atomicAdd(&cntS[(u >> 19) & (BROWS - 1)], 1);
        }
    }
    __syncthreads();

    // inclusive scan of the 1024 row-counts; exclusive(r) = cntS[r-1]
    for (int off = 1; off < BROWS; off <<= 1) {
        int t = 0;
        if (tid >= off) t = cntS[tid - off];
        __syncthreads();
        if (tid >= off) cntS[tid] += t;
        __syncthreads();
    }

    // emit row_ptr slice for this bucket (coalesced)
    int gr = (b << BSHIFT) + tid;
    if (gr < N_NODES)
        row_ptr[gr] = beg + (tid ? cntS[tid - 1] : 0);

    // phase B: scatter into LDS at final sorted position
#pragma unroll
    for (int j = 0; j < PITER; j++) {
        if (eu[j] != 0xFFFFFFFFu) {
            int r    = (int)((eu[j] >> 19) & (BROWS - 1));
            int base = (r == 0) ? 0 : cntS[r - 1];
            payS[base + elp[j]] = make_float2(__uint_as_float(eu[j] & 0x7FFFFu), ev[j]);
        }
    }
    __syncthreads();

    // phase C: stream out sequentially — full-line coalesced stores
    for (int i = tid; i < run; i += 1024) {
        edges[beg + i] = payS[i];
    }
}

// out = bufA = concat(user, item)
__global__ void init2_kernel(const float* __restrict__ user_t,
                             const float* __restrict__ item_t,
                             float* __restrict__ out,
                             float* __restrict__ bufA) {
    int i = blockIdx.x * blockDim.x + threadIdx.x;
    const int total4 = N_NODES * EMB / 4;
    if (i >= total4) return;
    int fi   = i * 4;
    int node = fi >> 6;
    int off  = fi & 63;
    float4 v;
    if (node < N_USERS)
        v = *(const float4*)(user_t + (size_t)node * EMB + off);
    else
        v = *(const float4*)(item_t + (size_t)(node - N_USERS) * EMB + off);
    *(float4*)(out  + fi) = v;
    *(float4*)(bufA + fi) = v;
}

// SpMM: 4 rows per wave; lane = (quarter q = row, slot s = dims 4s..4s+3).
// WY=false on the last layer skips the dead y write (-75 MB).
template<bool WY>
__global__ void spmm4_kernel(const int*    __restrict__ rp,
                             const float2* __restrict__ edges,
                             const float*  __restrict__ x,
                             float*        __restrict__ y,
                             float*        __restrict__ out,
                             float scale) {
    int t    = blockIdx.x * blockDim.x + threadIdx.x;
    int wid  = t >> 6;
    int lane = t & 63;
    int q    = lane >> 4;
    int s    = lane & 15;
    int row  = (wid << 2) + q;
    if (row >= N_NODES) return;
    int i   = rp[row];
    int end = rp[row + 1];
    float4 acc = make_float4(0.f, 0.f, 0.f, 0.f);
    for (; i + 1 < end; i += 2) {
        float2 e0 = edges[i];
        float2 e1 = edges[i + 1];
        float4 a = *(const float4*)(x + ((size_t)__float_as_int(e0.x) << 6) + (s << 2));
        float4 b = *(const float4*)(x + ((size_t)__float_as_int(e1.x) << 6) + (s << 2));
        acc.x += e0.y * a.x + e1.y * b.x;
        acc.y += e0.y * a.y + e1.y * b.y;
        acc.z += e0.y * a.z + e1.y * b.z;
        acc.w += e0.y * a.w + e1.y * b.w;
    }
    if (i < end) {
        float2 e0 = edges[i];
        float4 a = *(const float4*)(x + ((size_t)__float_as_int(e0.x) << 6) + (s << 2));
        acc.x += e0.y * a.x;
        acc.y += e0.y * a.y;
        acc.z += e0.y * a.z;
        acc.w += e0.y * a.w;
    }
    size_t o = ((size_t)row << 6) + (s << 2);
    if (WY) *(float4*)(y + o) = acc;
    float4 ov = *(float4*)(out + o);
    ov.x = (ov.x + acc.x) * scale;
    ov.y = (ov.y + acc.y) * scale;
    ov.z = (ov.z + acc.z) * scale;
    ov.w = (ov.w + acc.w) * scale;
    *(float4*)(out + o) = ov;
}

// ===========================================================================
// Fallback atomic path (tiny ws only)
// ===========================================================================
__global__ void init_kernel(const float* __restrict__ user_t,
                            const float* __restrict__ item_t,
                            float* __restrict__ out,
                            float* __restrict__ bufA,
                            float* __restrict__ bufB) {
    int i = blockIdx.x * blockDim.x + threadIdx.x;
    const int total4 = N_NODES * EMB / 4;
    if (i >= total4) return;
    int fi   = i * 4;
    int node = fi >> 6;
    int off  = fi & 63;
    float4 v;
    if (node < N_USERS)
        v = *(const float4*)(user_t + (size_t)node * EMB + off);
    else
        v = *(const float4*)(item_t + (size_t)(node - N_USERS) * EMB + off);
    *(float4*)(out  + fi) = v;
    *(float4*)(bufA + fi) = v;
    *(float4*)(bufB + fi) = make_float4(0.f, 0.f, 0.f, 0.f);
}

__global__ void spmm_kernel(const int*   __restrict__ rows,
                            const int*   __restrict__ cols,
                            const float* __restrict__ vals,
                            const float* __restrict__ x,
                            float*       __restrict__ y) {
    int tid  = blockIdx.x * blockDim.x + threadIdx.x;
    int e    = tid >> 6;
    int lane = tid & 63;
    if (e >= NNZ) return;
    atomicAdd(&y[(size_t)rows[e] * EMB + lane], vals[e] * x[(size_t)cols[e] * EMB + lane]);
}

__global__ void acc_zero_kernel(float* __restrict__ out,
                                const float* __restrict__ src,
                                float* __restrict__ zbuf) {
    int i = blockIdx.x * blockDim.x + threadIdx.x;
    const int total4 = N_NODES * EMB / 4;
    if (i >= total4) return;
    int fi = i * 4;
    float4 o = *(float4*)(out + fi);
    float4 s = *(const float4*)(src + fi);
    o.x += s.x; o.y += s.y; o.z += s.z; o.w += s.w;
    *(float4*)(out  + fi) = o;
    *(float4*)(zbuf + fi) = make_float4(0.f, 0.f, 0.f, 0.f);
}

__global__ void final_kernel(float* __restrict__ out,
                             const float* __restrict__ src) {
    int i = blockIdx.x * blockDim.x + threadIdx.x;
    const int total4 = N_NODES * EMB / 4;
    if (i >= total4) return;
    int fi = i * 4;
    float4 o = *(float4*)(out + fi);
    float4 s = *(const float4*)(src + fi);
    o.x = (o.x + s.x) * 0.25f;
    o.y = (o.y + s.y) * 0.25f;
    o.z = (o.z + s.z) * 0.25f;
    o.w = (o.w + s.w) * 0.25f;
    *(float4*)(out + fi) = o;
}

// ===========================================================================
extern "C" void kernel_launch(void* const* d_in, const int* in_sizes, int n_in,
                              void* d_out, int out_size, void* d_ws, size_t ws_size,
                              hipStream_t stream) {
    const float* user_t = (const float*)d_in[0];
    const float* item_t = (const float*)d_in[1];
    const int*   rows   = (const int*)d_in[2];
    const int*   cols   = (const int*)d_in[3];
    const float* vals   = (const float*)d_in[4];
    float* out = (float*)d_out;

    const size_t emb_elems = (size_t)N_NODES * EMB;
    const int total4    = N_NODES * EMB / 4;
    const int ew_blocks = (total4 + 255) / 256;

    // ---- workspace layout ----
    char* p = (char*)d_ws;
    float*  bufA      = (float*)p;  p += emb_elems * 4;           // 76.8 MB
    float*  bufB      = (float*)p;  p += emb_elems * 4;           // 76.8 MB
    float2* edges     = (float2*)p; p += (size_t)NNZ * 8;         // 32 MB
    int*    row_ptr   = (int*)p;    p += (size_t)(N_NODES + 1) * 4;
    int*    bcnt      = (int*)p;    p += (size_t)NBUCK * 16 * 4;  // padded
    int*    bbase     = (int*)p;    p += (size_t)(NBUCK + 1) * 4;
    size_t need = (size_t)(p - (char*)d_ws);

    // alias: segmented pay lives in bufB (dead until first spmm); 38.4 MB
    float2* pay = (float2*)bufB;

    if (ws_size >= need) {
        hipMemsetAsync(bcnt, 0, (size_t)NBUCK * 16 * 4, stream);
        bucket_agg_kernel<<<AGG_BLOCKS, AGG_THR, 0, stream>>>(rows, cols, vals, bcnt, pay);
        bscan_kernel<<<1, 512, 0, stream>>>(bcnt, bbase, row_ptr);
        place_kernel<<<NBUCK, 1024, 0, stream>>>(bcnt, bbase, pay, row_ptr, edges);

        init2_kernel<<<ew_blocks, 256, 0, stream>>>(user_t, item_t, out, bufA);

        const int spmm_blocks = (int)(((size_t)N_NODES / 4 * 64 + 255) / 256); // 18750
        spmm4_kernel<true ><<<spmm_blocks, 256, 0, stream>>>(row_ptr, edges, bufA, bufB, out, 1.0f);
        spmm4_kernel<true ><<<spmm_blocks, 256, 0, stream>>>(row_ptr, edges, bufB, bufA, out, 1.0f);
        spmm4_kernel<false><<<spmm_blocks, 256, 0, stream>>>(row_ptr, edges, bufA, bufB, out, 0.25f);
    } else {
        const int spmm_blocks = (int)(((size_t)NNZ * 64 + 255) / 256);
        init_kernel<<<ew_blocks, 256, 0, stream>>>(user_t, item_t, out, bufA, bufB);
        spmm_kernel<<<spmm_blocks, 256, 0, stream>>>(rows, cols, vals, bufA, bufB);
        acc_zero_kernel<<<ew_blocks, 256, 0, stream>>>(out, bufB, bufA);
        spmm_kernel<<<spmm_blocks, 256, 0, stream>>>(rows, cols, vals, bufB, bufA);
        acc_zero_kernel<<<ew_blocks, 256, 0, stream>>>(out, bufA, bufB);
        spmm_kernel<<<spmm_blocks, 256, 0, stream>>>(rows, cols, vals, bufA, bufB);
        final_kernel<<<ew_blocks, 256, 0, stream>>>(out, bufB);
    }
}

// Round 6
// 713.866 us; speedup vs baseline: 1.8178x; 1.0512x over previous
//
#include <hip/hip_runtime.h>

#define N_USERS 100000
#define N_ITEMS 200000
#define N_NODES (N_USERS + N_ITEMS)
#define EMB     64
#define NNZ     4000000

// coarse row-buckets: 1024 rows each
#define BSHIFT 10
#define BROWS  (1 << BSHIFT)                               // 1024 rows / bucket
#define NBUCK  ((N_NODES + BROWS - 1) >> BSHIFT)           // 293

// block-aggregated binning pass
#define AGG_THR    512
#define AGG_EPT    8
#define AGG_T      (AGG_THR * AGG_EPT)                     // 4096 edges / block
#define AGG_BLOCKS ((NNZ + AGG_T - 1) / AGG_T)             // 977
#define SCAN_N     512                                     // pow2 >= NBUCK

// bucket segment capacity (mean fill 13652, sigma ~117 -> +23 sigma headroom)
#define SEGCAP 16384
#define PCAP   SEGCAP
#define PITER  (PCAP / 1024)                               // 16

// NOTE (round-3 post-mortem): __builtin_nontemporal_load on gfx950 acts as a
// last-use/invalidating load; on dirty lines it caused ~35x WRITE_SIZE
// amplification. Plain cached accesses only.
// NOTE (round-4 post-mortem): 4M fine-grained global atomicAdds cost ~32B HBM
// write traffic each -- aggregate in LDS first; no per-edge global atomics.

// ===========================================================================
// CSR build (histogram-free, bucket-segmented)
// ===========================================================================
__global__ __launch_bounds__(AGG_THR)
void bucket_agg_kernel(const int*   __restrict__ rows,
                       const int*   __restrict__ cols,
                       const float* __restrict__ vals,
                       int*         __restrict__ bcnt,   // [NBUCK*16] zeroed
                       float2*      __restrict__ pay) {  // [NBUCK*SEGCAP]
    __shared__ int            cntS[SCAN_N];   // counts -> exclusive scan
    __shared__ int            hoff[SCAN_N];   // segment offset per bucket
    __shared__ float2         payS[AGG_T];    // staged (packed col, val)
    __shared__ unsigned short bidS[AGG_T];    // bucket id per staged slot

    int tid  = threadIdx.x;
    int base = blockIdx.x * AGG_T;

    for (int i = tid; i < SCAN_N; i += AGG_THR) cntS[i] = 0;
    __syncthreads();

    // phase A: count (keep per-edge bucket/row-lo/local-pos packed in regs)
    unsigned pk[AGG_EPT];
#pragma unroll
    for (int j = 0; j < AGG_EPT; j++) {
        int e = base + j * AGG_THR + tid;
        pk[j] = 0xFFFFFFFFu;
        if (e < NNZ) {
            int r  = rows[e];
            int b  = r >> BSHIFT;                    // 9 bits
            int lp = atomicAdd(&cntS[b], 1);         // <= 4095, 12 bits
            pk[j]  = ((unsigned)b << 22) | ((unsigned)(r & (BROWS - 1)) << 12)
                   | (unsigned)lp;
        }
    }
    __syncthreads();

    // exclusive scan of cntS (SCAN_N == AGG_THR, one element per thread)
    int v = cntS[tid];
    for (int off = 1; off < SCAN_N; off <<= 1) {
        int t = 0;
        if (tid >= off) t = cntS[tid - off];
        __syncthreads();
        if (tid >= off) cntS[tid] += t;
        __syncthreads();
    }
    int excl = cntS[tid] - v;

    // reserve segment runs (one atomic per non-empty bucket)
    if (tid < NBUCK && v > 0) hoff[tid] = atomicAdd(&bcnt[tid * 16], v);
    __syncthreads();
    cntS[tid] = excl;
    __syncthreads();

    // phase B: stage into LDS at counting-sort position
#pragma unroll
    for (int j = 0; j < AGG_EPT; j++) {
        if (pk[j] != 0xFFFFFFFFu) {
            int e   = base + j * AGG_THR + tid;
            int b   = pk[j] >> 22;
            int rl  = (pk[j] >> 12) & (BROWS - 1);
            int lp  = pk[j] & 0xFFF;
            int idx = cntS[b] + lp;
            unsigned packed = (unsigned)cols[e] | ((unsigned)rl << 19);
            payS[idx] = make_float2(__uint_as_float(packed), vals[e]);
            bidS[idx] = (unsigned short)b;
        }
    }
    __syncthreads();

    // write-out: contiguous per-bucket runs into fixed segments
    int total = NNZ - base; if (total > AGG_T) total = AGG_T;
    for (int i = tid; i < total; i += AGG_THR) {
        int b   = bidS[i];
        int pos = hoff[b] + (i - cntS[b]);
        if (pos < SEGCAP)   // 23-sigma safety clamp
            pay[(size_t)b * SEGCAP + pos] = payS[i];
    }
}

// tiny pass: exclusive-scan the 293 bucket totals -> bbase; seal row_ptr end.
__global__ void bscan_kernel(const int* __restrict__ bcnt,
                             int* __restrict__ bbase,
                             int* __restrict__ row_ptr) {
    __shared__ int s[512];
    int tid = threadIdx.x;
    int v = 0;
    if (tid < NBUCK) {
        v = bcnt[tid * 16];
        if (v > SEGCAP) v = SEGCAP;
    }
    s[tid] = v;
    __syncthreads();
    for (int off = 1; off < 512; off <<= 1) {
        int t = 0;
        if (tid >= off) t = s[tid - off];
        __syncthreads();
        if (tid >= off) s[tid] += t;
        __syncthreads();
    }
    if (tid < NBUCK) bbase[tid] = s[tid] - v;
    if (tid == 511) bbase[NBUCK] = s[511];
    if (tid == 0)   row_ptr[N_NODES] = NNZ;
}

// pass 2: one block per coarse bucket. Counting-sort the bucket's segment by
// row ENTIRELY IN LDS, emit row_ptr slice, stream sorted run out coalesced.
__global__ __launch_bounds__(1024)
void place_kernel(const int*    __restrict__ bcnt,
                  const int*    __restrict__ bbase,
                  const float2* __restrict__ pay,
                  int*          __restrict__ row_ptr,
                  float2*       __restrict__ edges) {
    __shared__ float2 payS[PCAP];   // 131072 B
    __shared__ int    cntS[BROWS];  //   4096 B
    int b   = blockIdx.x;
    int tid = threadIdx.x;
    int run = bcnt[b * 16]; if (run > PCAP) run = PCAP;
    int beg = bbase[b];
    const float2* seg = pay + (size_t)b * SEGCAP;

    cntS[tid] = 0;
    __syncthreads();

    unsigned eu[PITER]; float ev[PITER]; int elp[PITER];
#pragma unroll
    for (int j = 0; j < PITER; j++) {
        int i = j * 1024 + tid;
        eu[j] = 0xFFFFFFFFu;
        if (i < run) {
            float2 p = seg[i];
            unsigned u = __float_as_uint(p.x);
            eu[j] = u;
            ev[j] = p.y;
            elp[j] = atomicAdd(&cntS[(u >> 19) & (BROWS - 1)], 1);
        }
    }
    __syncthreads();

    for (int off = 1; off < BROWS; off <<= 1) {
        int t = 0;
        if (tid >= off) t = cntS[tid - off];
        __syncthreads();
        if (tid >= off) cntS[tid] += t;
        __syncthreads();
    }

    int gr = (b << BSHIFT) + tid;
    if (gr < N_NODES)
        row_ptr[gr] = beg + (tid ? cntS[tid - 1] : 0);

#pragma unroll
    for (int j = 0; j < PITER; j++) {
        if (eu[j] != 0xFFFFFFFFu) {
            int r    = (int)((eu[j] >> 19) & (BROWS - 1));
            int base = (r == 0) ? 0 : cntS[r - 1];
            payS[base + elp[j]] = make_float2(__uint_as_float(eu[j] & 0x7FFFFu), ev[j]);
        }
    }
    __syncthreads();

    for (int i = tid; i < run; i += 1024) {
        edges[beg + i] = payS[i];
    }
}

// ===========================================================================
// embedding init
// ===========================================================================
// tier A: bufA only (out is written once, by spmm_fin)
__global__ void initA_kernel(const float* __restrict__ user_t,
                             const float* __restrict__ item_t,
                             float* __restrict__ bufA) {
    int i = blockIdx.x * blockDim.x + threadIdx.x;
    const int total4 = N_NODES * EMB / 4;
    if (i >= total4) return;
    int fi   = i * 4;
    int node = fi >> 6;
    int off  = fi & 63;
    float4 v;
    if (node < N_USERS)
        v = *(const float4*)(user_t + (size_t)node * EMB + off);
    else
        v = *(const float4*)(item_t + (size_t)(node - N_USERS) * EMB + off);
    *(float4*)(bufA + fi) = v;
}

// tier B: out + bufA
__global__ void init2_kernel(const float* __restrict__ user_t,
                             const float* __restrict__ item_t,
                             float* __restrict__ out,
                             float* __restrict__ bufA) {
    int i = blockIdx.x * blockDim.x + threadIdx.x;
    const int total4 = N_NODES * EMB / 4;
    if (i >= total4) return;
    int fi   = i * 4;
    int node = fi >> 6;
    int off  = fi & 63;
    float4 v;
    if (node < N_USERS)
        v = *(const float4*)(user_t + (size_t)node * EMB + off);
    else
        v = *(const float4*)(item_t + (size_t)(node - N_USERS) * EMB + off);
    *(float4*)(out  + fi) = v;
    *(float4*)(bufA + fi) = v;
}

// ===========================================================================
// SpMM core: row-dot with 4-edge unroll (4 independent gathers in flight ->
// attacks the latency limit seen in r5: 4.03 TB/s at VALUBusy 16%).
// ===========================================================================
__device__ __forceinline__ float4 row_gather_acc(const int*    __restrict__ rp,
                                                 const float2* __restrict__ edges,
                                                 const float*  __restrict__ x,
                                                 int row, int s) {
    int i   = rp[row];
    int end = rp[row + 1];
    float4 acc = make_float4(0.f, 0.f, 0.f, 0.f);
    for (; i + 3 < end; i += 4) {
        float2 e0 = edges[i];
        float2 e1 = edges[i + 1];
        float2 e2 = edges[i + 2];
        float2 e3 = edges[i + 3];
        float4 a = *(const float4*)(x + ((size_t)__float_as_int(e0.x) << 6) + (s << 2));
        float4 b = *(const float4*)(x + ((size_t)__float_as_int(e1.x) << 6) + (s << 2));
        float4 c = *(const float4*)(x + ((size_t)__float_as_int(e2.x) << 6) + (s << 2));
        float4 d = *(const float4*)(x + ((size_t)__float_as_int(e3.x) << 6) + (s << 2));
        acc.x += e0.y * a.x + e1.y * b.x + e2.y * c.x + e3.y * d.x;
        acc.y += e0.y * a.y + e1.y * b.y + e2.y * c.y + e3.y * d.y;
        acc.z += e0.y * a.z + e1.y * b.z + e2.y * c.z + e3.y * d.z;
        acc.w += e0.y * a.w + e1.y * b.w + e2.y * c.w + e3.y * d.w;
    }
    for (; i < end; ++i) {
        float2 e0 = edges[i];
        float4 a = *(const float4*)(x + ((size_t)__float_as_int(e0.x) << 6) + (s << 2));
        acc.x += e0.y * a.x;
        acc.y += e0.y * a.y;
        acc.z += e0.y * a.z;
        acc.w += e0.y * a.w;
    }
    return acc;
}

// tier A layers 1,2: y = A*x only (no accumulator traffic)
__global__ void spmm_y_kernel(const int*    __restrict__ rp,
                              const float2* __restrict__ edges,
                              const float*  __restrict__ x,
                              float*        __restrict__ y) {
    int t    = blockIdx.x * blockDim.x + threadIdx.x;
    int wid  = t >> 6;
    int lane = t & 63;
    int q    = lane >> 4;
    int s    = lane & 15;
    int row  = (wid << 2) + q;
    if (row >= N_NODES) return;
    float4 acc = row_gather_acc(rp, edges, x, row, s);
    *(float4*)(y + (((size_t)row << 6) + (s << 2))) = acc;
}

// tier A layer 3 fused final: out = (e + y1 + y2 + A*y2) / 4
__global__ void spmm_fin_kernel(const int*    __restrict__ rp,
                                const float2* __restrict__ edges,
                                const float*  __restrict__ e,
                                const float*  __restrict__ y1,
                                const float*  __restrict__ y2,
                                float*        __restrict__ out) {
    int t    = blockIdx.x * blockDim.x + threadIdx.x;
    int wid  = t >> 6;
    int lane = t & 63;
    int q    = lane >> 4;
    int s    = lane & 15;
    int row  = (wid << 2) + q;
    if (row >= N_NODES) return;
    float4 acc = row_gather_acc(rp, edges, y2, row, s);
    size_t o = ((size_t)row << 6) + (s << 2);
    float4 ev = *(const float4*)(e  + o);
    float4 v1 = *(const float4*)(y1 + o);
    float4 v2 = *(const float4*)(y2 + o);
    float4 r;
    r.x = (ev.x + v1.x + v2.x + acc.x) * 0.25f;
    r.y = (ev.y + v1.y + v2.y + acc.y) * 0.25f;
    r.z = (ev.z + v1.z + v2.z + acc.z) * 0.25f;
    r.w = (ev.w + v1.w + v2.w + acc.w) * 0.25f;
    *(float4*)(out + o) = r;
}

// tier B (round-5 schedule): y-write + out RMW per layer
template<bool WY>
__global__ void spmm4_kernel(const int*    __restrict__ rp,
                             const float2* __restrict__ edges,
                             const float*  __restrict__ x,
                             float*        __restrict__ y,
                             float*        __restrict__ out,
                             float scale) {
    int t    = blockIdx.x * blockDim.x + threadIdx.x;
    int wid  = t >> 6;
    int lane = t & 63;
    int q    = lane >> 4;
    int s    = lane & 15;
    int row  = (wid << 2) + q;
    if (row >= N_NODES) return;
    float4 acc = row_gather_acc(rp, edges, x, row, s);
    size_t o = ((size_t)row << 6) + (s << 2);
    if (WY) *(float4*)(y + o) = acc;
    float4 ov = *(float4*)(out + o);
    ov.x = (ov.x + acc.x) * scale;
    ov.y = (ov.y + acc.y) * scale;
    ov.z = (ov.z + acc.z) * scale;
    ov.w = (ov.w + acc.w) * scale;
    *(float4*)(out + o) = ov;
}

// ===========================================================================
// Fallback atomic path (tiny ws only)
// ===========================================================================
__global__ void init_kernel(const float* __restrict__ user_t,
                            const float* __restrict__ item_t,
                            float* __restrict__ out,
                            float* __restrict__ bufA,
                            float* __restrict__ bufB) {
    int i = blockIdx.x * blockDim.x + threadIdx.x;
    const int total4 = N_NODES * EMB / 4;
    if (i >= total4) return;
    int fi   = i * 4;
    int node = fi >> 6;
    int off  = fi & 63;
    float4 v;
    if (node < N_USERS)
        v = *(const float4*)(user_t + (size_t)node * EMB + off);
    else
        v = *(const float4*)(item_t + (size_t)(node - N_USERS) * EMB + off);
    *(float4*)(out  + fi) = v;
    *(float4*)(bufA + fi) = v;
    *(float4*)(bufB + fi) = make_float4(0.f, 0.f, 0.f, 0.f);
}

__global__ void spmm_kernel(const int*   __restrict__ rows,
                            const int*   __restrict__ cols,
                            const float* __restrict__ vals,
                            const float* __restrict__ x,
                            float*       __restrict__ y) {
    int tid  = blockIdx.x * blockDim.x + threadIdx.x;
    int e    = tid >> 6;
    int lane = tid & 63;
    if (e >= NNZ) return;
    atomicAdd(&y[(size_t)rows[e] * EMB + lane], vals[e] * x[(size_t)cols[e] * EMB + lane]);
}

__global__ void acc_zero_kernel(float* __restrict__ out,
                                const float* __restrict__ src,
                                float* __restrict__ zbuf) {
    int i = blockIdx.x * blockDim.x + threadIdx.x;
    const int total4 = N_NODES * EMB / 4;
    if (i >= total4) return;
    int fi = i * 4;
    float4 o = *(float4*)(out + fi);
    float4 s = *(const float4*)(src + fi);
    o.x += s.x; o.y += s.y; o.z += s.z; o.w += s.w;
    *(float4*)(out  + fi) = o;
    *(float4*)(zbuf + fi) = make_float4(0.f, 0.f, 0.f, 0.f);
}

__global__ void final_kernel(float* __restrict__ out,
                             const float* __restrict__ src) {
    int i = blockIdx.x * blockDim.x + threadIdx.x;
    const int total4 = N_NODES * EMB / 4;
    if (i >= total4) return;
    int fi = i * 4;
    float4 o = *(float4*)(out + fi);
    float4 s = *(const float4*)(src + fi);
    o.x = (o.x + s.x) * 0.25f;
    o.y = (o.y + s.y) * 0.25f;
    o.z = (o.z + s.z) * 0.25f;
    o.w = (o.w + s.w) * 0.25f;
    *(float4*)(out + fi) = o;
}

// ===========================================================================
extern "C" void kernel_launch(void* const* d_in, const int* in_sizes, int n_in,
                              void* d_out, int out_size, void* d_ws, size_t ws_size,
                              hipStream_t stream) {
    const float* user_t = (const float*)d_in[0];
    const float* item_t = (const float*)d_in[1];
    const int*   rows   = (const int*)d_in[2];
    const int*   cols   = (const int*)d_in[3];
    const float* vals   = (const float*)d_in[4];
    float* out = (float*)d_out;

    const size_t emb_bytes = (size_t)N_NODES * EMB * 4;           // 76.8 MB
    const int total4    = N_NODES * EMB / 4;
    const int ew_blocks = (total4 + 255) / 256;
    const size_t small_bytes = (size_t)(N_NODES + 1) * 4          // row_ptr
                             + (size_t)NBUCK * 16 * 4             // bcnt
                             + (size_t)(NBUCK + 1) * 4;           // bbase
    const size_t edges_bytes = (size_t)NNZ * 8;                   // 32 MB

    const size_t need_A = 3 * emb_bytes + edges_bytes + small_bytes; // ~264 MB
    const size_t need_B = 2 * emb_bytes + edges_bytes + small_bytes; // ~187 MB

    const int spmm_blocks = (int)(((size_t)N_NODES / 4 * 64 + 255) / 256); // 18750

    if (ws_size >= need_A) {
        // ---- tier A: deferred accumulator (3 embedding buffers) ----
        char* p = (char*)d_ws;
        float*  bufA    = (float*)p; p += emb_bytes;   // e
        float*  bufB    = (float*)p; p += emb_bytes;   // y1
        float*  bufC    = (float*)p; p += emb_bytes;   // y2 (pay aliases here)
        float2* edges   = (float2*)p; p += edges_bytes;
        int*    row_ptr = (int*)p;   p += (size_t)(N_NODES + 1) * 4;
        int*    bcnt    = (int*)p;   p += (size_t)NBUCK * 16 * 4;
        int*    bbase   = (int*)p;
        float2* pay     = (float2*)bufC;               // dead before L2 writes y2

        hipMemsetAsync(bcnt, 0, (size_t)NBUCK * 16 * 4, stream);
        bucket_agg_kernel<<<AGG_BLOCKS, AGG_THR, 0, stream>>>(rows, cols, vals, bcnt, pay);
        bscan_kernel<<<1, 512, 0, stream>>>(bcnt, bbase, row_ptr);
        place_kernel<<<NBUCK, 1024, 0, stream>>>(bcnt, bbase, pay, row_ptr, edges);

        initA_kernel<<<ew_blocks, 256, 0, stream>>>(user_t, item_t, bufA);

        spmm_y_kernel  <<<spmm_blocks, 256, 0, stream>>>(row_ptr, edges, bufA, bufB);
        spmm_y_kernel  <<<spmm_blocks, 256, 0, stream>>>(row_ptr, edges, bufB, bufC);
        spmm_fin_kernel<<<spmm_blocks, 256, 0, stream>>>(row_ptr, edges, bufA, bufB, bufC, out);
    } else if (ws_size >= need_B) {
        // ---- tier B: round-5 schedule ----
        char* p = (char*)d_ws;
        float*  bufA    = (float*)p; p += emb_bytes;
        float*  bufB    = (float*)p; p += emb_bytes;
        float2* edges   = (float2*)p; p += edges_bytes;
        int*    row_ptr = (int*)p;   p += (size_t)(N_NODES + 1) * 4;
        int*    bcnt    = (int*)p;   p += (size_t)NBUCK * 16 * 4;
        int*    bbase   = (int*)p;
        float2* pay     = (float2*)bufB;

        hipMemsetAsync(bcnt, 0, (size_t)NBUCK * 16 * 4, stream);
        bucket_agg_kernel<<<AGG_BLOCKS, AGG_THR, 0, stream>>>(rows, cols, vals, bcnt, pay);
        bscan_kernel<<<1, 512, 0, stream>>>(bcnt, bbase, row_ptr);
        place_kernel<<<NBUCK, 1024, 0, stream>>>(bcnt, bbase, pay, row_ptr, edges);

        init2_kernel<<<ew_blocks, 256, 0, stream>>>(user_t, item_t, out, bufA);

        spmm4_kernel<true ><<<spmm_blocks, 256, 0, stream>>>(row_ptr, edges, bufA, bufB, out, 1.0f);
        spmm4_kernel<true ><<<spmm_blocks, 256, 0, stream>>>(row_ptr, edges, bufB, bufA, out, 1.0f);
        spmm4_kernel<false><<<spmm_blocks, 256, 0, stream>>>(row_ptr, edges, bufA, bufB, out, 0.25f);
    } else {
        // ---- tiny-ws fallback ----
        char* p = (char*)d_ws;
        float* bufA = (float*)p; p += emb_bytes;
        float* bufB = (float*)p;
        const int spmmA_blocks = (int)(((size_t)NNZ * 64 + 255) / 256);
        init_kernel<<<ew_blocks, 256, 0, stream>>>(user_t, item_t, out, bufA, bufB);
        spmm_kernel<<<spmmA_blocks, 256, 0, stream>>>(rows, cols, vals, bufA, bufB);
        acc_zero_kernel<<<ew_blocks, 256, 0, stream>>>(out, bufB, bufA);
        spmm_kernel<<<spmmA_blocks, 256, 0, stream>>>(rows, cols, vals, bufB, bufA);
        acc_zero_kernel<<<ew_blocks, 256, 0, stream>>>(out, bufA, bufB);
        spmm_kernel<<<spmmA_blocks, 256, 0, stream>>>(rows, cols, vals, bufA, bufB);
        final_kernel<<<ew_blocks, 256, 0, stream>>>(out, bufB);
    }
}

// Round 7
// 511.598 us; speedup vs baseline: 2.5365x; 1.3954x over previous
//
#include <hip/hip_runtime.h>

#define N_USERS 100000
#define N_ITEMS 200000
#define N_NODES (N_USERS + N_ITEMS)
#define EMB     64
#define NNZ     4000000

// coarse row-buckets: 1024 rows each
#define BSHIFT 10
#define BROWS  (1 << BSHIFT)                               // 1024 rows / bucket
#define NBUCK  ((N_NODES + BROWS - 1) >> BSHIFT)           // 293

// block-aggregated binning pass
#define AGG_THR    512
#define AGG_EPT    8
#define AGG_T      (AGG_THR * AGG_EPT)                     // 4096 edges / block
#define AGG_BLOCKS ((NNZ + AGG_T - 1) / AGG_T)             // 977
#define SCAN_N     512                                     // pow2 >= NBUCK

// bucket segment capacity (mean fill 13652, sigma ~117 -> +23 sigma headroom)
#define SEGCAP 16384
#define PCAP   SEGCAP
#define PITER  (PCAP / 1024)                               // 16

typedef _Float16 h4 __attribute__((ext_vector_type(4)));   // 8B vector of fp16

// NOTE (r3 post-mortem): __builtin_nontemporal_load on gfx950 = last-use/
// invalidating; on dirty lines -> ~35x WRITE amplification. Plain loads only.
// NOTE (r4 post-mortem): per-edge global atomics cost ~32B HBM each.
// NOTE (r6 post-mortem): gather is DRAM-efficiency-bound (~4 TB/s random
// 256B reads; unroll 2->4 changed nothing). Only byte-reduction helps ->
// fp16 gather sources below. Linear e term stays fp32 (read from tables).

// ===========================================================================
// CSR build (histogram-free, bucket-segmented)
// ===========================================================================
__global__ __launch_bounds__(AGG_THR)
void bucket_agg_kernel(const int*   __restrict__ rows,
                       const int*   __restrict__ cols,
                       const float* __restrict__ vals,
                       int*         __restrict__ bcnt,   // [NBUCK*16] zeroed
                       float2*      __restrict__ pay) {  // [NBUCK*SEGCAP]
    __shared__ int            cntS[SCAN_N];   // counts -> exclusive scan
    __shared__ int            hoff[SCAN_N];   // segment offset per bucket
    __shared__ float2         payS[AGG_T];    // staged (packed col, val)
    __shared__ unsigned short bidS[AGG_T];    // bucket id per staged slot

    int tid  = threadIdx.x;
    int base = blockIdx.x * AGG_T;

    for (int i = tid; i < SCAN_N; i += AGG_THR) cntS[i] = 0;
    __syncthreads();

    // phase A: count (keep per-edge bucket/row-lo/local-pos packed in regs)
    unsigned pk[AGG_EPT];
#pragma unroll
    for (int j = 0; j < AGG_EPT; j++) {
        int e = base + j * AGG_THR + tid;
        pk[j] = 0xFFFFFFFFu;
        if (e < NNZ) {
            int r  = rows[e];
            int b  = r >> BSHIFT;                    // 9 bits
            int lp = atomicAdd(&cntS[b], 1);         // <= 4095, 12 bits
            pk[j]  = ((unsigned)b << 22) | ((unsigned)(r & (BROWS - 1)) << 12)
                   | (unsigned)lp;
        }
    }
    __syncthreads();

    // exclusive scan of cntS (SCAN_N == AGG_THR, one element per thread)
    int v = cntS[tid];
    for (int off = 1; off < SCAN_N; off <<= 1) {
        int t = 0;
        if (tid >= off) t = cntS[tid - off];
        __syncthreads();
        if (tid >= off) cntS[tid] += t;
        __syncthreads();
    }
    int excl = cntS[tid] - v;

    // reserve segment runs (one atomic per non-empty bucket)
    if (tid < NBUCK && v > 0) hoff[tid] = atomicAdd(&bcnt[tid * 16], v);
    __syncthreads();
    cntS[tid] = excl;
    __syncthreads();

    // phase B: stage into LDS at counting-sort position
#pragma unroll
    for (int j = 0; j < AGG_EPT; j++) {
        if (pk[j] != 0xFFFFFFFFu) {
            int e   = base + j * AGG_THR + tid;
            int b   = pk[j] >> 22;
            int rl  = (pk[j] >> 12) & (BROWS - 1);
            int lp  = pk[j] & 0xFFF;
            int idx = cntS[b] + lp;
            unsigned packed = (unsigned)cols[e] | ((unsigned)rl << 19);
            payS[idx] = make_float2(__uint_as_float(packed), vals[e]);
            bidS[idx] = (unsigned short)b;
        }
    }
    __syncthreads();

    // write-out: contiguous per-bucket runs into fixed segments
    int total = NNZ - base; if (total > AGG_T) total = AGG_T;
    for (int i = tid; i < total; i += AGG_THR) {
        int b   = bidS[i];
        int pos = hoff[b] + (i - cntS[b]);
        if (pos < SEGCAP)   // 23-sigma safety clamp
            pay[(size_t)b * SEGCAP + pos] = payS[i];
    }
}

// tiny pass: exclusive-scan the 293 bucket totals -> bbase; seal row_ptr end.
__global__ void bscan_kernel(const int* __restrict__ bcnt,
                             int* __restrict__ bbase,
                             int* __restrict__ row_ptr) {
    __shared__ int s[512];
    int tid = threadIdx.x;
    int v = 0;
    if (tid < NBUCK) {
        v = bcnt[tid * 16];
        if (v > SEGCAP) v = SEGCAP;
    }
    s[tid] = v;
    __syncthreads();
    for (int off = 1; off < 512; off <<= 1) {
        int t = 0;
        if (tid >= off) t = s[tid - off];
        __syncthreads();
        if (tid >= off) s[tid] += t;
        __syncthreads();
    }
    if (tid < NBUCK) bbase[tid] = s[tid] - v;
    if (tid == 511) bbase[NBUCK] = s[511];
    if (tid == 0)   row_ptr[N_NODES] = NNZ;
}

// pass 2: one block per coarse bucket. Counting-sort the bucket's segment by
// row ENTIRELY IN LDS, emit row_ptr slice, stream sorted run out coalesced.
__global__ __launch_bounds__(1024)
void place_kernel(const int*    __restrict__ bcnt,
                  const int*    __restrict__ bbase,
                  const float2* __restrict__ pay,
                  int*          __restrict__ row_ptr,
                  float2*       __restrict__ edges) {
    __shared__ float2 payS[PCAP];   // 131072 B
    __shared__ int    cntS[BROWS];  //   4096 B
    int b   = blockIdx.x;
    int tid = threadIdx.x;
    int run = bcnt[b * 16]; if (run > PCAP) run = PCAP;
    int beg = bbase[b];
    const float2* seg = pay + (size_t)b * SEGCAP;

    cntS[tid] = 0;
    __syncthreads();

    unsigned eu[PITER]; float ev[PITER]; int elp[PITER];
#pragma unroll
    for (int j = 0; j < PITER; j++) {
        int i = j * 1024 + tid;
        eu[j] = 0xFFFFFFFFu;
        if (i < run) {
            float2 p = seg[i];
            unsigned u = __float_as_uint(p.x);
            eu[j] = u;
            ev[j] = p.y;
            elp[j] = atomicAdd(&cntS[(u >> 19) & (BROWS - 1)], 1);
        }
    }
    __syncthreads();

    for (int off = 1; off < BROWS; off <<= 1) {
        int t = 0;
        if (tid >= off) t = cntS[tid - off];
        __syncthreads();
        if (tid >= off) cntS[tid] += t;
        __syncthreads();
    }

    int gr = (b << BSHIFT) + tid;
    if (gr < N_NODES)
        row_ptr[gr] = beg + (tid ? cntS[tid - 1] : 0);

#pragma unroll
    for (int j = 0; j < PITER; j++) {
        if (eu[j] != 0xFFFFFFFFu) {
            int r    = (int)((eu[j] >> 19) & (BROWS - 1));
            int base = (r == 0) ? 0 : cntS[r - 1];
            payS[base + elp[j]] = make_float2(__uint_as_float(eu[j] & 0x7FFFFu), ev[j]);
        }
    }
    __syncthreads();

    for (int i = tid; i < run; i += 1024) {
        edges[beg + i] = payS[i];
    }
}

// ===========================================================================
// fp16 embedding shadow: e_h = fp16(concat(user, item))
// ===========================================================================
__global__ void initH_kernel(const float* __restrict__ user_t,
                             const float* __restrict__ item_t,
                             _Float16* __restrict__ eh) {
    int i = blockIdx.x * blockDim.x + threadIdx.x;
    const int total4 = N_NODES * EMB / 4;
    if (i >= total4) return;
    int fi   = i * 4;
    int node = fi >> 6;
    int off  = fi & 63;
    float4 v;
    if (node < N_USERS)
        v = *(const float4*)(user_t + (size_t)node * EMB + off);
    else
        v = *(const float4*)(item_t + (size_t)(node - N_USERS) * EMB + off);
    h4 h = { (_Float16)v.x, (_Float16)v.y, (_Float16)v.z, (_Float16)v.w };
    *(h4*)(eh + fi) = h;
}

// ===========================================================================
// SpMM core: fp16 gather source (128B/row), fp32 accumulate.
// ===========================================================================
__device__ __forceinline__ float4 row_gather_h(const int*      __restrict__ rp,
                                               const float2*   __restrict__ edges,
                                               const _Float16* __restrict__ xh,
                                               int row, int s) {
    int i   = rp[row];
    int end = rp[row + 1];
    float4 acc = make_float4(0.f, 0.f, 0.f, 0.f);
    for (; i + 3 < end; i += 4) {
        float2 e0 = edges[i];
        float2 e1 = edges[i + 1];
        float2 e2 = edges[i + 2];
        float2 e3 = edges[i + 3];
        h4 a = *(const h4*)(xh + ((size_t)__float_as_int(e0.x) << 6) + (s << 2));
        h4 b = *(const h4*)(xh + ((size_t)__float_as_int(e1.x) << 6) + (s << 2));
        h4 c = *(const h4*)(xh + ((size_t)__float_as_int(e2.x) << 6) + (s << 2));
        h4 d = *(const h4*)(xh + ((size_t)__float_as_int(e3.x) << 6) + (s << 2));
        acc.x += e0.y * (float)a.x + e1.y * (float)b.x + e2.y * (float)c.x + e3.y * (float)d.x;
        acc.y += e0.y * (float)a.y + e1.y * (float)b.y + e2.y * (float)c.y + e3.y * (float)d.y;
        acc.z += e0.y * (float)a.z + e1.y * (float)b.z + e2.y * (float)c.z + e3.y * (float)d.z;
        acc.w += e0.y * (float)a.w + e1.y * (float)b.w + e2.y * (float)c.w + e3.y * (float)d.w;
    }
    for (; i < end; ++i) {
        float2 e0 = edges[i];
        h4 a = *(const h4*)(xh + ((size_t)__float_as_int(e0.x) << 6) + (s << 2));
        acc.x += e0.y * (float)a.x;
        acc.y += e0.y * (float)a.y;
        acc.z += e0.y * (float)a.z;
        acc.w += e0.y * (float)a.w;
    }
    return acc;
}

// layers 1,2: y_h = fp16(A * x_h)
__global__ void spmm_yh_kernel(const int*      __restrict__ rp,
                               const float2*   __restrict__ edges,
                               const _Float16* __restrict__ xh,
                               _Float16*       __restrict__ yh) {
    int t    = blockIdx.x * blockDim.x + threadIdx.x;
    int wid  = t >> 6;
    int lane = t & 63;
    int q    = lane >> 4;
    int s    = lane & 15;
    int row  = (wid << 2) + q;
    if (row >= N_NODES) return;
    float4 acc = row_gather_h(rp, edges, xh, row, s);
    h4 h = { (_Float16)acc.x, (_Float16)acc.y, (_Float16)acc.z, (_Float16)acc.w };
    *(h4*)(yh + (((size_t)row << 6) + (s << 2))) = h;
}

// layer 3 fused final: out = (e_fp32 + y1 + y2 + A*y2) / 4
// e read straight from the input tables in fp32 (dominant term keeps full
// precision; also kills the 150MB initA copy pass).
__global__ void spmm_fin_kernel(const int*      __restrict__ rp,
                                const float2*   __restrict__ edges,
                                const float*    __restrict__ user_t,
                                const float*    __restrict__ item_t,
                                const _Float16* __restrict__ y1h,
                                const _Float16* __restrict__ y2h,
                                float*          __restrict__ out) {
    int t    = blockIdx.x * blockDim.x + threadIdx.x;
    int wid  = t >> 6;
    int lane = t & 63;
    int q    = lane >> 4;
    int s    = lane & 15;
    int row  = (wid << 2) + q;
    if (row >= N_NODES) return;
    float4 acc = row_gather_h(rp, edges, y2h, row, s);
    size_t o = ((size_t)row << 6) + (s << 2);
    float4 ev;
    if (row < N_USERS)
        ev = *(const float4*)(user_t + o);
    else
        ev = *(const float4*)(item_t + o - ((size_t)N_USERS << 6));
    h4 v1 = *(const h4*)(y1h + o);
    h4 v2 = *(const h4*)(y2h + o);
    float4 r;
    r.x = (ev.x + (float)v1.x + (float)v2.x + acc.x) * 0.25f;
    r.y = (ev.y + (float)v1.y + (float)v2.y + acc.y) * 0.25f;
    r.z = (ev.z + (float)v1.z + (float)v2.z + acc.z) * 0.25f;
    r.w = (ev.w + (float)v1.w + (float)v2.w + acc.w) * 0.25f;
    *(float4*)(out + o) = r;
}

// ===========================================================================
// Fallback atomic path (tiny ws only)
// ===========================================================================
__global__ void init_kernel(const float* __restrict__ user_t,
                            const float* __restrict__ item_t,
                            float* __restrict__ out,
                            float* __restrict__ bufA,
                            float* __restrict__ bufB) {
    int i = blockIdx.x * blockDim.x + threadIdx.x;
    const int total4 = N_NODES * EMB / 4;
    if (i >= total4) return;
    int fi   = i * 4;
    int node = fi >> 6;
    int off  = fi & 63;
    float4 v;
    if (node < N_USERS)
        v = *(const float4*)(user_t + (size_t)node * EMB + off);
    else
        v = *(const float4*)(item_t + (size_t)(node - N_USERS) * EMB + off);
    *(float4*)(out  + fi) = v;
    *(float4*)(bufA + fi) = v;
    *(float4*)(bufB + fi) = make_float4(0.f, 0.f, 0.f, 0.f);
}

__global__ void spmm_kernel(const int*   __restrict__ rows,
                            const int*   __restrict__ cols,
                            const float* __restrict__ vals,
                            const float* __restrict__ x,
                            float*       __restrict__ y) {
    int tid  = blockIdx.x * blockDim.x + threadIdx.x;
    int e    = tid >> 6;
    int lane = tid & 63;
    if (e >= NNZ) return;
    atomicAdd(&y[(size_t)rows[e] * EMB + lane], vals[e] * x[(size_t)cols[e] * EMB + lane]);
}

__global__ void acc_zero_kernel(float* __restrict__ out,
                                const float* __restrict__ src,
                                float* __restrict__ zbuf) {
    int i = blockIdx.x * blockDim.x + threadIdx.x;
    const int total4 = N_NODES * EMB / 4;
    if (i >= total4) return;
    int fi = i * 4;
    float4 o = *(float4*)(out + fi);
    float4 s = *(const float4*)(src + fi);
    o.x += s.x; o.y += s.y; o.z += s.z; o.w += s.w;
    *(float4*)(out  + fi) = o;
    *(float4*)(zbuf + fi) = make_float4(0.f, 0.f, 0.f, 0.f);
}

__global__ void final_kernel(float* __restrict__ out,
                             const float* __restrict__ src) {
    int i = blockIdx.x * blockDim.x + threadIdx.x;
    const int total4 = N_NODES * EMB / 4;
    if (i >= total4) return;
    int fi = i * 4;
    float4 o = *(float4*)(out + fi);
    float4 s = *(const float4*)(src + fi);
    o.x = (o.x + s.x) * 0.25f;
    o.y = (o.y + s.y) * 0.25f;
    o.z = (o.z + s.z) * 0.25f;
    o.w = (o.w + s.w) * 0.25f;
    *(float4*)(out + fi) = o;
}

// ===========================================================================
extern "C" void kernel_launch(void* const* d_in, const int* in_sizes, int n_in,
                              void* d_out, int out_size, void* d_ws, size_t ws_size,
                              hipStream_t stream) {
    const float* user_t = (const float*)d_in[0];
    const float* item_t = (const float*)d_in[1];
    const int*   rows   = (const int*)d_in[2];
    const int*   cols   = (const int*)d_in[3];
    const float* vals   = (const float*)d_in[4];
    float* out = (float*)d_out;

    const size_t embh_bytes = (size_t)N_NODES * EMB * 2;          // 38.4 MB
    const size_t emb_bytes  = (size_t)N_NODES * EMB * 4;          // 76.8 MB
    const size_t pay_bytes  = (size_t)NBUCK * SEGCAP * 8;         // 38.4 MB
    const size_t r0_bytes   = (pay_bytes > embh_bytes ? pay_bytes : embh_bytes);
    const size_t edges_bytes = (size_t)NNZ * 8;                   // 32 MB
    const size_t small_bytes = (size_t)(N_NODES + 1) * 4
                             + (size_t)NBUCK * 16 * 4
                             + (size_t)(NBUCK + 1) * 4;
    const int total4    = N_NODES * EMB / 4;
    const int ew_blocks = (total4 + 255) / 256;

    const size_t need_h = r0_bytes + 2 * embh_bytes + edges_bytes + small_bytes; // ~148 MB
    const int spmm_blocks = (int)(((size_t)N_NODES / 4 * 64 + 255) / 256); // 18750

    if (ws_size >= need_h) {
        // ---- fp16-gather tier ----
        char* p = (char*)d_ws;
        char*     region0 = p;           p += r0_bytes;  // pay, then e_h
        _Float16* y1h     = (_Float16*)p; p += embh_bytes;
        _Float16* y2h     = (_Float16*)p; p += embh_bytes;
        float2*   edges   = (float2*)p;   p += edges_bytes;
        int*      row_ptr = (int*)p;      p += (size_t)(N_NODES + 1) * 4;
        int*      bcnt    = (int*)p;      p += (size_t)NBUCK * 16 * 4;
        int*      bbase   = (int*)p;
        float2*   pay = (float2*)region0;          // dead after place
        _Float16* eh  = (_Float16*)region0;        // built after place

        hipMemsetAsync(bcnt, 0, (size_t)NBUCK * 16 * 4, stream);
        bucket_agg_kernel<<<AGG_BLOCKS, AGG_THR, 0, stream>>>(rows, cols, vals, bcnt, pay);
        bscan_kernel<<<1, 512, 0, stream>>>(bcnt, bbase, row_ptr);
        place_kernel<<<NBUCK, 1024, 0, stream>>>(bcnt, bbase, pay, row_ptr, edges);

        initH_kernel<<<ew_blocks, 256, 0, stream>>>(user_t, item_t, eh);

        spmm_yh_kernel <<<spmm_blocks, 256, 0, stream>>>(row_ptr, edges, eh,  y1h);
        spmm_yh_kernel <<<spmm_blocks, 256, 0, stream>>>(row_ptr, edges, y1h, y2h);
        spmm_fin_kernel<<<spmm_blocks, 256, 0, stream>>>(row_ptr, edges, user_t, item_t,
                                                         y1h, y2h, out);
    } else {
        // ---- tiny-ws fallback ----
        char* p = (char*)d_ws;
        float* bufA = (float*)p; p += emb_bytes;
        float* bufB = (float*)p;
        const int spmmA_blocks = (int)(((size_t)NNZ * 64 + 255) / 256);
        init_kernel<<<ew_blocks, 256, 0, stream>>>(user_t, item_t, out, bufA, bufB);
        spmm_kernel<<<spmmA_blocks, 256, 0, stream>>>(rows, cols, vals, bufA, bufB);
        acc_zero_kernel<<<ew_blocks, 256, 0, stream>>>(out, bufB, bufA);
        spmm_kernel<<<spmmA_blocks, 256, 0, stream>>>(rows, cols, vals, bufB, bufA);
        acc_zero_kernel<<<ew_blocks, 256, 0, stream>>>(out, bufA, bufB);
        spmm_kernel<<<spmmA_blocks, 256, 0, stream>>>(rows, cols, vals, bufA, bufB);
        final_kernel<<<ew_blocks, 256, 0, stream>>>(out, bufB);
    }
}